// Round 3
// baseline (924.870 us; speedup 1.0000x reference)
//
#include <hip/hip_runtime.h>
#include <type_traits>
#include <cstdint>
#include <cstddef>

// ---- types ----
typedef __bf16 bf16x8 __attribute__((ext_vector_type(8)));
typedef float  f32x4  __attribute__((ext_vector_type(4)));
typedef unsigned short u16v4 __attribute__((ext_vector_type(4)));
typedef unsigned short u16v8 __attribute__((ext_vector_type(8)));

#define H    2048
#define NH   16
#define NKV  8
#define HD   128
#define II   8192
#define S    2048

__device__ __forceinline__ unsigned short f2bf(float f) {
    union { float f; unsigned u; } v; v.f = f;
    unsigned r = v.u + 0x7fffu + ((v.u >> 16) & 1u);
    return (unsigned short)(r >> 16);
}
__device__ __forceinline__ float bf2f(unsigned short b) {
    union { unsigned u; float f; } v; v.u = ((unsigned)b) << 16;
    return v.f;
}

// async global->LDS, 16B per lane. LDS dest must be wave-uniform base;
// HW adds lane*16.
__device__ __forceinline__ void async16(const unsigned short* g, const unsigned short* l) {
    __builtin_amdgcn_global_load_lds(
        (const __attribute__((address_space(1))) void*)g,
        (__attribute__((address_space(3))) void*)l, 16, 0, 0);
}

// ---------------- weight fp32 -> bf16 (8 elems/thread) ----------------
__global__ __launch_bounds__(256) void w2bf(const float* __restrict__ src,
                                            unsigned short* __restrict__ dst)
{
    const size_t i = (size_t)blockIdx.x * 256 + threadIdx.x;
    float4 a = ((const float4*)src)[2 * i];
    float4 b = ((const float4*)src)[2 * i + 1];
    u16v8 o;
    o[0] = f2bf(a.x); o[1] = f2bf(a.y); o[2] = f2bf(a.z); o[3] = f2bf(a.w);
    o[4] = f2bf(b.x); o[5] = f2bf(b.y); o[6] = f2bf(b.z); o[7] = f2bf(b.w);
    ((u16v8*)dst)[i] = o;
}

// ---- mlp weights fp32 -> bf16 with up/gate interleave for 256-row B-tiles ----
__global__ __launch_bounds__(256) void w2bf_mlp256(const float* __restrict__ src,
                                                   unsigned short* __restrict__ dst)
{
    const int p = blockIdx.x;
    const int g = p >> 8, r = p & 255;
    const int half = r >> 7;
    const int c = (g << 7) + (r & 127);
    const float* s = src + ((size_t)half * II + c) * H;
    unsigned short* d = dst + (size_t)p * H;
    const int t = threadIdx.x;
    float4 a = ((const float4*)s)[2 * t];
    float4 b = ((const float4*)s)[2 * t + 1];
    u16v8 o;
    o[0] = f2bf(a.x); o[1] = f2bf(a.y); o[2] = f2bf(a.z); o[3] = f2bf(a.w);
    o[4] = f2bf(b.x); o[5] = f2bf(b.y); o[6] = f2bf(b.z); o[7] = f2bf(b.w);
    *(u16v8*)&d[t * 8] = o;
}

// ---------------- RMSNorm: fp32 in -> bf16 out ----------------
__global__ __launch_bounds__(256) void rmsnorm_kernel(
    const float* __restrict__ x, const float* __restrict__ w,
    unsigned short* __restrict__ out)
{
    __shared__ float red[4];
    const int row = blockIdx.x;
    const int tid = threadIdx.x;
    const float* xr = x + (size_t)row * H;
    float4 v0 = ((const float4*)xr)[tid];
    float4 v1 = ((const float4*)xr)[256 + tid];
    float s = v0.x*v0.x + v0.y*v0.y + v0.z*v0.z + v0.w*v0.w
            + v1.x*v1.x + v1.y*v1.y + v1.z*v1.z + v1.w*v1.w;
    #pragma unroll
    for (int o = 1; o < 64; o <<= 1) s += __shfl_xor(s, o);
    if ((tid & 63) == 0) red[tid >> 6] = s;
    __syncthreads();
    float tot = red[0] + red[1] + red[2] + red[3];
    float rinv = rsqrtf(tot * (1.0f / (float)H) + 1e-6f);
    float4 w0 = ((const float4*)w)[tid];
    float4 w1 = ((const float4*)w)[256 + tid];
    u16v4 o0, o1;
    o0[0] = f2bf(v0.x * w0.x * rinv); o0[1] = f2bf(v0.y * w0.y * rinv);
    o0[2] = f2bf(v0.z * w0.z * rinv); o0[3] = f2bf(v0.w * w0.w * rinv);
    o1[0] = f2bf(v1.x * w1.x * rinv); o1[1] = f2bf(v1.y * w1.y * rinv);
    o1[2] = f2bf(v1.z * w1.z * rinv); o1[3] = f2bf(v1.w * w1.w * rinv);
    unsigned short* orow = out + (size_t)row * H;
    *(u16v4*)&orow[tid * 4]        = o0;
    *(u16v4*)&orow[1024 + tid * 4] = o1;
}

// ---------------- partial-sum reduce: out[i] += sum_j P[j][i] ----------------
template<int NP>
__global__ __launch_bounds__(256) void reduce_add(float* __restrict__ out,
                                                  const float* __restrict__ P)
{
    const size_t i = (size_t)blockIdx.x * 256 + threadIdx.x;   // float4 index
    float4 o = ((float4*)out)[i];
    #pragma unroll
    for (int j = 0; j < NP; ++j) {
        float4 p = ((const float4*)(P + (size_t)j * S * H))[i];
        o.x += p.x; o.y += p.y; o.z += p.z; o.w += p.w;
    }
    ((float4*)out)[i] = o;
}

// ---------------- GEMM (m97 structure, kept for QKV / O-proj) ----------------
template<typename OutT, bool ATOMIC, bool SILU, bool SWAP, bool PARTK>
__global__ __launch_bounds__(256) void gemm_bf16(
    const unsigned short* __restrict__ A, const unsigned short* __restrict__ B,
    OutT* __restrict__ C, const float* __restrict__ R, float* __restrict__ P,
    int M, int N, int K, int lda, int kslice)
{
    __shared__ unsigned short SM[8192];       // As = SM[0..4095], Bs = SM[4096..8191]
    unsigned short* As = SM;
    unsigned short* Bs = SM + 4096;
    const int tid  = threadIdx.x;
    const int wave = tid >> 6, lane = tid & 63;
    const int quad = lane >> 4, l16 = lane & 15;
    const int nt = SWAP ? blockIdx.y : blockIdx.x;
    const int mt = SWAP ? blockIdx.x : blockIdx.y;
    const int m0 = mt * 128, n0 = nt * 128;
    const int wm = (wave >> 1) * 64, wn = (wave & 1) * 64;
    const int kbeg = blockIdx.z * kslice;

    const int sr = lane >> 2;          // row within 16-row group
    const int sc = (lane & 3) * 8;     // col elems 0,8,16,24
    const unsigned short* Ag0 = A + (size_t)(m0 + wave * 16 + sr) * lda + sc + kbeg;
    const unsigned short* Ag1 = Ag0 + (size_t)64 * lda;
    const unsigned short* Bg0 = B + (size_t)(n0 + wave * 16 + sr) * K + sc + kbeg;
    const unsigned short* Bg1 = Bg0 + (size_t)64 * K;
    const unsigned short* Al0 = &As[(wave * 16) * 32];        // wave-uniform bases
    const unsigned short* Al1 = &As[(64 + wave * 16) * 32];
    const unsigned short* Bl0 = &Bs[(wave * 16) * 32];
    const unsigned short* Bl1 = &Bs[(64 + wave * 16) * 32];

    f32x4 acc[4][4] = {};

    for (int k0 = 0; k0 < kslice; k0 += 32) {
        async16(Ag0 + k0, Al0);
        async16(Ag1 + k0, Al1);
        async16(Bg0 + k0, Bl0);
        async16(Bg1 + k0, Bl1);
        __syncthreads();

        bf16x8 af[4], bfm[4];
        #pragma unroll
        for (int i = 0; i < 4; i++)
            af[i] = *(const bf16x8*)&As[(wm + i * 16 + l16) * 32 + quad * 8];
        #pragma unroll
        for (int i = 0; i < 4; i++)
            bfm[i] = *(const bf16x8*)&Bs[(wn + i * 16 + l16) * 32 + quad * 8];
        #pragma unroll
        for (int mi = 0; mi < 4; mi++)
            #pragma unroll
            for (int ni = 0; ni < 4; ni++)
                acc[mi][ni] = __builtin_amdgcn_mfma_f32_16x16x32_bf16(
                    af[mi], bfm[ni], acc[mi][ni], 0, 0, 0);
        __syncthreads();
    }

    #pragma unroll
    for (int mi = 0; mi < 4; mi++) {
        #pragma unroll
        for (int r = 0; r < 4; r++) {
            const int m = m0 + wm + mi * 16 + quad * 4 + r;
            const size_t rowoff = (size_t)m * N;
            #pragma unroll
            for (int ni = 0; ni < 4; ni++) {
                const int n = n0 + wn + ni * 16 + l16;
                float v = acc[mi][ni][r];
                if constexpr (PARTK) {
                    if (blockIdx.z == 0) {
                        float base = R ? R[rowoff + n] : ((const float*)C)[rowoff + n];
                        ((float*)C)[rowoff + n] = base + v;
                    } else {
                        P[(size_t)(blockIdx.z - 1) * ((size_t)M * N) + rowoff + n] = v;
                    }
                } else if constexpr (ATOMIC) {
                    if (R != nullptr && blockIdx.z == 0) v += R[rowoff + n];
                    atomicAdd((float*)&C[rowoff + n], v);
                } else if constexpr (std::is_same<OutT, float>::value) {
                    C[rowoff + n] = v;
                } else {
                    C[rowoff + n] = f2bf(v);
                }
            }
        }
    }
}

// ---------------- 256x256 8-phase GEMM, asymmetric-depth pipeline -------------
// BM=BN=256, BK=64, 512 thr = 8 waves (2M x 4N), acc[8][4].
// LDS = A 2-slot dbuf (64 KiB) + B 3-slot tbuf (96 KiB) = 160 KiB exactly.
// A (activations, L2/L3-resident, ~200-450cy) staged 1 tile ahead;
// B (HBM-streamed weights, ~900cy) staged 2 tiles ahead.
//
// Issue order per tile t: p0 = [Aset0(t+1), Aset1(t+1)] (4 loads),
//                         p1 = [Bset0(t+2), Bset1(t+2)] (4 loads).
// Aset0 = groups {0-7,16-23} (rows 0-63,128-191)  = q(0x) A-rows
// Aset1 = groups {8-15,24-31}                      = q(1x) A-rows
// Bset0 = groups {0-3,8-11,16-19,24-27} (rows 0-31,64-95,128-159,192-223) = q(x0)
// Bset1 = complement                                = q(x1)
// Queue trace (steady, oldest->newest at t.p1-end):
//   [Aset1(t) | Bset0(t+1) Bset1(t+1) | Aset0(t+1) Aset1(t+1) | Bset0(t+2) Bset1(t+2)] = 14
//   vmcnt(12) retires Aset1(t) (5 phases old; needed t.p2).
// At t.p3-end: queue = 12; vmcnt(6) retires B(t+1) (6-7 phases) + Aset0(t+1)
//   (3 phases, L2-OK) -> leaves [Aset1(t+1), B(t+2)] = 6.
// Tail (t+2>=nkt: no B staged): t=nkt-2: p1-end vmcnt(8), p3-end vmcnt(2);
//   t=nkt-1: p1-end vmcnt(0). All traced for correctness.
template<typename OutT, bool ATOMIC, bool SILU, bool PARTK>
__global__ __launch_bounds__(512, 2) void gemm256(
    const unsigned short* __restrict__ A, const unsigned short* __restrict__ B,
    OutT* __restrict__ C, const float* __restrict__ R, float* __restrict__ P,
    int M, int N, int K, int lda, int kslice)
{
    __shared__ unsigned short SM[81920];   // A: [0,32768) 2 slots; B: [32768,81920) 3 slots
    const int tid  = threadIdx.x;
    const int wave = tid >> 6, lane = tid & 63;
    const int quad = lane >> 4, l16 = lane & 15;
    const int wm = wave >> 2, wn = wave & 3;

    // T1: bijective XCD swizzle; M-tile fast so consecutive ids share a B-panel.
    const int nMt = gridDim.x;
    const int nwg = nMt * gridDim.y;
    const int orig = blockIdx.y * nMt + blockIdx.x;
    const int q8 = nwg >> 3, r8 = nwg & 7;
    const int xcd = orig & 7, lid = orig >> 3;
    const int wgid = (xcd < r8 ? xcd * (q8 + 1) : r8 * (q8 + 1) + (xcd - r8) * q8) + lid;
    const int mt = wgid % nMt, ntile = wgid / nMt;
    const int m0 = mt * 256, n0 = ntile * 256;
    const int kbeg = blockIdx.z * kslice;

    // staging: row-group = 8 rows x 64 cols = one wave async16.
    // lane l writes stored block (l&7) of row base+(l>>3); stored = logical ^
    // (row&7), row&7 == l>>3 => source block = (l&7)^(l>>3).
    const int rIn  = lane >> 3;
    const int cBlk = ((lane & 7) ^ rIn) * 8;
    const unsigned short* Ab = A + (size_t)(m0 + rIn) * lda + kbeg + cBlk;
    const unsigned short* Bb = B + (size_t)(n0 + rIn) * K   + kbeg + cBlk;
    const int ga0 = wave,      ga1 = 16 + wave;    // Aset0
    const int ga2 = 8 + wave,  ga3 = 24 + wave;    // Aset1
    const int gbB = (wave & 3) + ((wave >> 2) << 4);
    const int gb0 = gbB, gb1 = gbB + 8;            // Bset0
    const int gb2 = gbB + 4, gb3 = gbB + 12;       // Bset1

    auto stgA = [&](int g, int kt, int s) {
        async16(Ab + (size_t)g * 8 * lda + kt * 64, &SM[s * 16384 + g * 512]);
    };
    auto stgB = [&](int g, int kt, int s) {
        async16(Bb + (size_t)g * 8 * K + kt * 64, &SM[32768 + s * 16384 + g * 512]);
    };

    // fragment read addressing (stored block = logical ^ (row&7))
    const int rx   = l16 & 7;
    const int blk0 = (quad ^ rx) * 8;           // ks=0
    const int blk1 = ((4 | quad) ^ rx) * 8;     // ks=1
    const int rowA = (wm * 128 + l16) * 64;
    const int rowB = (wn * 64 + l16) * 64;

    f32x4 acc[8][4] = {};
    const int nkt = kslice >> 6;

    // prologue: B(0)->bslot0, B(1)->bslot1, A(0)->aslot0; full drain (cold).
    stgB(gb0, 0, 0); stgB(gb1, 0, 0); stgB(gb2, 0, 0); stgB(gb3, 0, 0);
    if (1 < nkt) { stgB(gb0, 1, 1); stgB(gb1, 1, 1); stgB(gb2, 1, 1); stgB(gb3, 1, 1); }
    stgA(ga0, 0, 0); stgA(ga1, 0, 0); stgA(ga2, 0, 0); stgA(ga3, 0, 0);
    asm volatile("s_waitcnt vmcnt(0)" ::: "memory");
    __builtin_amdgcn_s_barrier();

    for (int t = 0; t < nkt; ++t) {
        const unsigned short* Ac = &SM[(t & 1) * 16384];
        const unsigned short* Bc = &SM[32768 + (t % 3) * 16384];
        const int an = (t + 1) & 1;
        const int bn = (t + 2) % 3;
        const bool moreA = (t + 1 < nkt);
        const bool moreB = (t + 2 < nkt);
        bf16x8 af[4][2], bg[4][2];

        // ===== phase 0: read A(mi0-3)+B(ni0-1); stage A(t+1) x4; MFMA q(00)
        #pragma unroll
        for (int mi = 0; mi < 4; ++mi) {
            af[mi][0] = *(const bf16x8*)&Ac[rowA + mi * 1024 + blk0];
            af[mi][1] = *(const bf16x8*)&Ac[rowA + mi * 1024 + blk1];
        }
        #pragma unroll
        for (int ni = 0; ni < 2; ++ni) {
            bg[ni][0] = *(const bf16x8*)&Bc[rowB + ni * 1024 + blk0];
            bg[ni][1] = *(const bf16x8*)&Bc[rowB + ni * 1024 + blk1];
        }
        if (moreA) {
            stgA(ga0, t + 1, an); stgA(ga1, t + 1, an);
            stgA(ga2, t + 1, an); stgA(ga3, t + 1, an);
        }
        __builtin_amdgcn_s_barrier();
        asm volatile("s_waitcnt lgkmcnt(0)" ::: "memory");
        __builtin_amdgcn_sched_barrier(0);
        __builtin_amdgcn_s_setprio(1);
        #pragma unroll
        for (int mi = 0; mi < 4; ++mi)
            #pragma unroll
            for (int ni = 0; ni < 2; ++ni) {
                acc[mi][ni] = __builtin_amdgcn_mfma_f32_16x16x32_bf16(af[mi][0], bg[ni][0], acc[mi][ni], 0, 0, 0);
                acc[mi][ni] = __builtin_amdgcn_mfma_f32_16x16x32_bf16(af[mi][1], bg[ni][1], acc[mi][ni], 0, 0, 0);
            }
        __builtin_amdgcn_s_setprio(0);
        __builtin_amdgcn_s_barrier();

        // ===== phase 1: read B(ni2-3); stage B(t+2) x4; MFMA q(01); derived wait
        #pragma unroll
        for (int ni = 2; ni < 4; ++ni) {
            bg[ni][0] = *(const bf16x8*)&Bc[rowB + ni * 1024 + blk0];
            bg[ni][1] = *(const bf16x8*)&Bc[rowB + ni * 1024 + blk1];
        }
        if (moreB) {
            stgB(gb0, t + 2, bn); stgB(gb1, t + 2, bn);
            stgB(gb2, t + 2, bn); stgB(gb3, t + 2, bn);
        }
        __builtin_amdgcn_s_barrier();
        asm volatile("s_waitcnt lgkmcnt(0)" ::: "memory");
        __builtin_amdgcn_sched_barrier(0);
        __builtin_amdgcn_s_setprio(1);
        #pragma unroll
        for (int mi = 0; mi < 4; ++mi)
            #pragma unroll
            for (int ni = 2; ni < 4; ++ni) {
                acc[mi][ni] = __builtin_amdgcn_mfma_f32_16x16x32_bf16(af[mi][0], bg[ni][0], acc[mi][ni], 0, 0, 0);
                acc[mi][ni] = __builtin_amdgcn_mfma_f32_16x16x32_bf16(af[mi][1], bg[ni][1], acc[mi][ni], 0, 0, 0);
            }
        __builtin_amdgcn_s_setprio(0);
        if (moreB)      { asm volatile("s_waitcnt vmcnt(12)" ::: "memory"); }
        else if (moreA) { asm volatile("s_waitcnt vmcnt(8)"  ::: "memory"); }
        else            { asm volatile("s_waitcnt vmcnt(0)"  ::: "memory"); }
        __builtin_amdgcn_s_barrier();

        // ===== phase 2: read A(mi4-7); MFMA q(10)
        #pragma unroll
        for (int mi = 0; mi < 4; ++mi) {
            af[mi][0] = *(const bf16x8*)&Ac[rowA + (4 + mi) * 1024 + blk0];
            af[mi][1] = *(const bf16x8*)&Ac[rowA + (4 + mi) * 1024 + blk1];
        }
        __builtin_amdgcn_s_barrier();
        asm volatile("s_waitcnt lgkmcnt(0)" ::: "memory");
        __builtin_amdgcn_sched_barrier(0);
        __builtin_amdgcn_s_setprio(1);
        #pragma unroll
        for (int mi = 0; mi < 4; ++mi)
            #pragma unroll
            for (int ni = 0; ni < 2; ++ni) {
                acc[4 + mi][ni] = __builtin_amdgcn_mfma_f32_16x16x32_bf16(af[mi][0], bg[ni][0], acc[4 + mi][ni], 0, 0, 0);
                acc[4 + mi][ni] = __builtin_amdgcn_mfma_f32_16x16x32_bf16(af[mi][1], bg[ni][1], acc[4 + mi][ni], 0, 0, 0);
            }
        __builtin_amdgcn_s_setprio(0);
        __builtin_amdgcn_s_barrier();

        // ===== phase 3: MFMA q(11); derived wait
        __builtin_amdgcn_s_setprio(1);
        #pragma unroll
        for (int mi = 0; mi < 4; ++mi)
            #pragma unroll
            for (int ni = 2; ni < 4; ++ni) {
                acc[4 + mi][ni] = __builtin_amdgcn_mfma_f32_16x16x32_bf16(af[mi][0], bg[ni][0], acc[4 + mi][ni], 0, 0, 0);
                acc[4 + mi][ni] = __builtin_amdgcn_mfma_f32_16x16x32_bf16(af[mi][1], bg[ni][1], acc[4 + mi][ni], 0, 0, 0);
            }
        __builtin_amdgcn_s_setprio(0);
        if (moreB)      { asm volatile("s_waitcnt vmcnt(6)" ::: "memory"); }
        else if (moreA) { asm volatile("s_waitcnt vmcnt(2)" ::: "memory"); }
        __builtin_amdgcn_s_barrier();
    }

    if constexpr (SILU) {
        // B-tile rows 0-127 = up (wn 0,1), 128-255 = gate (wn 2,3).
        unsigned short* Ex = SM;                      // 256*132*2 B = 66 KiB
        if (wn >= 2) {
            #pragma unroll
            for (int mi = 0; mi < 8; ++mi)
                #pragma unroll
                for (int r = 0; r < 4; ++r) {
                    const int rl = wm * 128 + mi * 16 + quad * 4 + r;
                    #pragma unroll
                    for (int ni = 0; ni < 4; ++ni)
                        Ex[rl * 132 + (wn - 2) * 64 + ni * 16 + l16] = f2bf(acc[mi][ni][r]);
                }
        }
        __builtin_amdgcn_s_barrier();
        if (wn < 2) {
            #pragma unroll
            for (int mi = 0; mi < 8; ++mi)
                #pragma unroll
                for (int r = 0; r < 4; ++r) {
                    const int rl = wm * 128 + mi * 16 + quad * 4 + r;
                    const size_t rowoff = (size_t)(m0 + rl) * N;
                    #pragma unroll
                    for (int ni = 0; ni < 4; ++ni) {
                        const int cl = wn * 64 + ni * 16 + l16;
                        float g = bf2f(Ex[rl * 132 + cl]);
                        float u = acc[mi][ni][r];
                        float sig = 1.0f / (1.0f + exp2f(-g * 1.4426950408889634f));
                        C[rowoff + (n0 >> 1) + cl] = f2bf(g * sig * u);
                    }
                }
        }
        return;
    }

    #pragma unroll
    for (int mi = 0; mi < 8; ++mi) {
        #pragma unroll
        for (int r = 0; r < 4; ++r) {
            const int m = m0 + wm * 128 + mi * 16 + quad * 4 + r;
            const size_t rowoff = (size_t)m * N;
            #pragma unroll
            for (int ni = 0; ni < 4; ++ni) {
                const int n = n0 + wn * 64 + ni * 16 + l16;
                float v = acc[mi][ni][r];
                if constexpr (PARTK) {
                    if (blockIdx.z == 0) {
                        float base = R ? R[rowoff + n] : ((const float*)C)[rowoff + n];
                        ((float*)C)[rowoff + n] = base + v;
                    } else {
                        P[(size_t)(blockIdx.z - 1) * ((size_t)M * N) + rowoff + n] = v;
                    }
                } else if constexpr (ATOMIC) {
                    if (R != nullptr && blockIdx.z == 0) v += R[rowoff + n];
                    atomicAdd((float*)&C[rowoff + n], v);
                } else if constexpr (std::is_same<OutT, float>::value) {
                    C[rowoff + n] = v;
                } else {
                    C[rowoff + n] = f2bf(v);
                }
            }
        }
    }
}

// ---------------- RoPE prep: qkv bf16 [S,4096] -> q_r [NH,S,HD], k_r [NKV,S,HD] ----
__global__ __launch_bounds__(256) void rope_prep(
    const unsigned short* __restrict__ qkv, const float* __restrict__ cosp,
    const float* __restrict__ sinp,
    unsigned short* __restrict__ q_r, unsigned short* __restrict__ k_r)
{
    const int s = blockIdx.x;
    const int tid = threadIdx.x;
    const unsigned short* row = qkv + (size_t)s * 4096;
    #pragma unroll
    for (int j = 0; j < 12; j++) {          // 3072 = q(2048) + k(1024)
        int e = j * 256 + tid;
        int head = e >> 7, hd = e & 127;
        float v = bf2f(row[e]);
        float part = (hd < 64) ? -bf2f(row[e + 64]) : bf2f(row[e - 64]);
        float c  = cosp[s * HD + hd];
        float sn = sinp[s * HD + hd];
        unsigned short ob = f2bf(v * c + part * sn);
        if (head < NH) q_r[((size_t)head * S + s) * HD + hd] = ob;
        else           k_r[((size_t)(head - NH) * S + s) * HD + hd] = ob;
    }
}

// ---------------- V transpose: qkv bf16 cols 3072..4095 -> v_t TILED bf16 ----------
__global__ __launch_bounds__(256) void v_trans(
    const unsigned short* __restrict__ qkv, unsigned short* __restrict__ v_t)
{
    __shared__ unsigned short t[128][66];
    const int s0 = blockIdx.x * 64;
    const int kv = blockIdx.y;
    const int tid = threadIdx.x;
    const unsigned short* base = qkv + 3072 + kv * HD;
    #pragma unroll
    for (int i = 0; i < 4; i++) {
        int idx = i * 256 + tid;            // one u16v8 each, 1024 total
        int s_l = idx >> 4;
        int hd8 = (idx & 15) * 8;
        u16v8 v = *(const u16v8*)(base + (size_t)(s0 + s_l) * 4096 + hd8);
        #pragma unroll
        for (int j = 0; j < 8; j++) t[hd8 + j][s_l] = v[j];
    }
    __syncthreads();
    #pragma unroll
    for (int i = 0; i < 8; i++) {
        int idx = i * 256 + tid;            // 2048 u16v4 chunks
        int d  = idx >> 4;                  // 0..127
        int rm = idx & 15;
        int hh = rm >> 3;                   // key-tile half 0/1
        int s4 = (rm & 7) * 4;              // 0..28 within tile
        u16v4 o;
        o[0] = t[d][hh * 32 + s4];     o[1] = t[d][hh * 32 + s4 + 1];
        o[2] = t[d][hh * 32 + s4 + 2]; o[3] = t[d][hh * 32 + s4 + 3];
        size_t tile = (size_t)kv * (S / 32) + (s0 >> 5) + hh;
        *(u16v4*)&v_t[(tile * 128 + d) * 32 + s4] = o;
    }
}

// ---------------- Flash attention (LDS-staged K/V, swizzled) ----------------
__global__ __launch_bounds__(256) void attn_kernel(
    const unsigned short* __restrict__ q_r, const unsigned short* __restrict__ k_r,
    const unsigned short* __restrict__ v_t, unsigned short* __restrict__ out)
{
    __shared__ unsigned short Ks[32 * 128];
    __shared__ unsigned short Vs[144 * 32];
    __shared__ unsigned short P[4][16][40];
    const int h = blockIdx.y, kv = h >> 1;
    const int qb0 = blockIdx.x * 64;
    const int tid = threadIdx.x;
    const int wave = tid >> 6, lane = tid & 63, quad = lane >> 4, l16 = lane & 15;
    const int qb = qb0 + wave * 16;
    const unsigned short* Q  = q_r + (size_t)h * S * HD;
    const unsigned short* K  = k_r + (size_t)kv * S * HD;
    const unsigned short* Vh = v_t + (size_t)kv * (S / 32) * (128 * 32);

    // ones rows for the l-sum tile (rows 129..143 zero)
    {
        int e0 = tid * 2;
        Vs[128 * 32 + e0]     = (e0     < 32) ? (unsigned short)0x3F80 : (unsigned short)0;
        Vs[128 * 32 + e0 + 1] = (e0 + 1 < 32) ? (unsigned short)0x3F80 : (unsigned short)0;
    }

    bf16x8 aq[4];
    #pragma unroll
    for (int t = 0; t < 4; t++)
        aq[t] = *(const bf16x8*)&Q[(size_t)(qb + l16) * HD + t * 32 + quad * 8];

    f32x4 o[9] = {};                       // o[8] = row-sum accumulator (l)
    float m_i[4] = { -__builtin_inff(), -__builtin_inff(), -__builtin_inff(), -__builtin_inff() };
    const float SCL = 0.08838834764831845f * 1.4426950408889634f;  // 1/sqrt(HD)*log2(e)
    const int nk = (qb0 >> 5) + 2;

    const int kr  = (lane >> 4);           // K: row within 4-row issue group
    const int kbl = lane & 15;             // K: 16B block within 256B row
    const int vr  = (lane >> 2);           // V: row within 16-row issue group
    const int vbl = lane & 3;              // V: 16B block within 64B row

    for (int kb = 0; kb < nk; kb++) {
        const int kbase = kb * 32;
        const unsigned short* Ktile = K + (size_t)kbase * HD;
        const unsigned short* Vtile = Vh + (size_t)kb * (128 * 32);
        #pragma unroll
        for (int e = 0; e < 2; e++) {
            int r = wave * 8 + e * 4 + kr;
            async16(Ktile + r * 128 + ((kbl ^ (r & 15)) * 8), &Ks[(wave * 8 + e * 4) * 128]);
        }
        #pragma unroll
        for (int e = 0; e < 2; e++) {
            int d = wave * 32 + e * 16 + vr;
            async16(Vtile + d * 32 + ((vbl ^ (d & 3)) * 8), &Vs[(wave * 32 + e * 16) * 32]);
        }
        __syncthreads();   // vmcnt(0) drain: tiles landed

        if (kbase <= qb + 15) {
            f32x4 s0 = {0.f, 0.f, 0.f, 0.f}, s1 = {0.f, 0.f, 0.f, 0.f};
            #pragma unroll
            for (int t = 0; t < 4; t++) {
                int b = t * 4 + quad;
                bf16x8 b0 = *(const bf16x8*)&Ks[l16 * 128 + ((b ^ l16) * 8)];
                bf16x8 b1 = *(const bf16x8*)&Ks[(16 + l16) * 128 + ((b ^ l16) * 8)];
                s0 = __builtin_amdgcn_mfma_f32_16x16x32_bf16(aq[t], b0, s0, 0, 0, 0);
                s1 = __builtin_amdgcn_mfma_f32_16x16x32_bf16(aq[t], b1, s1, 0, 0, 0);
            }
            float alpha[4];
            #pragma unroll
            for (int r = 0; r < 4; r++) {
                const int q = qb + quad * 4 + r;
                float v0 = (kbase + l16      <= q) ? s0[r] * SCL : -__builtin_inff();
                float v1 = (kbase + 16 + l16 <= q) ? s1[r] * SCL : -__builtin_inff();
                float mx = fmaxf(v0, v1);
                #pragma unroll
                for (int d = 1; d < 16; d <<= 1) mx = fmaxf(mx, __shfl_xor(mx, d));
                float nm = fmaxf(m_i[r], mx);
                alpha[r] = exp2f(m_i[r] - nm);
                m_i[r] = nm;
                s0[r] = exp2f(v0 - nm);
                s1[r] = exp2f(v1 - nm);
            }
            #pragma unroll
            for (int ni = 0; ni < 9; ni++)
                #pragma unroll
                for (int r = 0; r < 4; r++) o[ni][r] *= alpha[r];
            #pragma unroll
            for (int r = 0; r < 4; r++) {
                P[wave][quad * 4 + r][l16]      = f2bf(s0[r]);
                P[wave][quad * 4 + r][16 + l16] = f2bf(s1[r]);
            }
            asm volatile("s_waitcnt lgkmcnt(0)" ::: "memory");
            bf16x8 ap = *(const bf16x8*)&P[wave][l16][quad * 8];
            #pragma unroll
            for (int ni = 0; ni < 9; ni++) {
                int d = ni * 16 + l16;
                bf16x8 bv = *(const bf16x8*)&Vs[d * 32 + ((quad ^ (d & 3)) * 8)];
                o[ni] = __builtin_amdgcn_mfma_f32_16x16x32_bf16(ap, bv, o[ni], 0, 0, 0);
            }
        }
        __syncthreads();   // all waves done reading before next tile staged
    }
    #pragma unroll
    for (int r = 0; r < 4; r++) {
        float lsum = __shfl(o[8][r], quad * 16);   // l lives in lane (l16=0, quad)
        const float inv = 1.0f / lsum;
        const int qrow = qb + quad * 4 + r;
        #pragma unroll
        for (int ni = 0; ni < 8; ni++)
            out[(size_t)qrow * (NH * HD) + h * HD + ni * 16 + l16] = f2bf(o[ni][r] * inv);
    }
}

// ---------------- launch ----------------
// ws map (MiB): [0,64) Wbuf | [16,32) P_o (O-proj partial, inside dead Wbuf-hi)
// [32,80) P_d (down partials x3; dead Wbuf-hi + x_norm + qkv by step 8)
// [64,72) x_norm | [72,88) qkv | [88,96) q_r | [96,100) k_r | [100,104) v_t
// [104,112) attn_o | [96,128) act (overlaps k_r/v_t/attn_o; all dead by step 7)
extern "C" void kernel_launch(void* const* d_in, const int* in_sizes, int n_in,
                              void* d_out, int out_size, void* d_ws, size_t ws_size,
                              hipStream_t stream) {
    const float* hs   = (const float*)d_in[0];   // [1,S,H] fp32
    const float* W    = (const float*)d_in[1];   // flat weights fp32
    const float* ln1  = (const float*)d_in[2];
    const float* ln2  = (const float*)d_in[3];
    const float* cosp = (const float*)d_in[4];   // [S,HD]
    const float* sinp = (const float*)d_in[5];
    float* out = (float*)d_out;                  // [S,H] fp32
    char* ws = (char*)d_ws;

    unsigned short* Wbuf   = (unsigned short*)(ws + 0);
    float*          P_o    = (float*)(ws + (16ull << 20));
    float*          P_d    = (float*)(ws + (32ull << 20));
    unsigned short* x_norm = (unsigned short*)(ws + (64ull  << 20));
    unsigned short* qkv    = (unsigned short*)(ws + (72ull  << 20));
    unsigned short* q_r    = (unsigned short*)(ws + (88ull  << 20));
    unsigned short* k_r    = (unsigned short*)(ws + (96ull  << 20));
    unsigned short* v_t    = (unsigned short*)(ws + (100ull << 20));
    unsigned short* attn_o = (unsigned short*)(ws + (104ull << 20));
    unsigned short* act    = (unsigned short*)(ws + (96ull  << 20));

    // 1. stage qkv weights -> bf16 ; input RMSNorm
    w2bf<<<8388608 / 2048, 256, 0, stream>>>(W, Wbuf);
    rmsnorm_kernel<<<S, 256, 0, stream>>>(hs, ln1, x_norm);
    // 2. fused QKV GEMM -> qkv bf16 [S,4096]
    gemm_bf16<unsigned short, false, false, true, false><<<dim3(S / 128, 4096 / 128, 1), 256, 0, stream>>>(
        x_norm, Wbuf, qkv, nullptr, nullptr, S, 4096, H, H, H);
    // 3. RoPE + layouts
    rope_prep<<<S, 256, 0, stream>>>(qkv, cosp, sinp, q_r, k_r);
    v_trans<<<dim3(S / 64, NKV), 256, 0, stream>>>(qkv, v_t);
    // 4. causal flash attention
    attn_kernel<<<dim3(S / 64, NH), 256, 0, stream>>>(q_r, k_r, v_t, attn_o);
    // 5. O-proj: out = hs + attn_o @ o_w^T  (split-K=2, partial buffer, no atomics)
    w2bf<<<4194304 / 2048, 256, 0, stream>>>(W + 8388608, Wbuf);
    gemm_bf16<float, false, false, false, true><<<dim3(H / 128, S / 128, 2), 256, 0, stream>>>(
        attn_o, Wbuf, out, hs, P_o, S, H, H, H, H / 2);
    reduce_add<1><<<(S * H / 4) / 256, 256, 0, stream>>>(out, P_o);
    // 6. post RMSNorm
    rmsnorm_kernel<<<S, 256, 0, stream>>>(out, ln2, x_norm);
    // 7. fused up|gate GEMM + SiLU epilogue -> act bf16 [S, II]  (256^2, deep B)
    w2bf_mlp256<<<2 * II, 256, 0, stream>>>(W + 12582912, Wbuf);
    gemm256<unsigned short, false, true, false><<<dim3(S / 256, (2 * II) / 256, 1), 512, 0, stream>>>(
        x_norm, Wbuf, act, nullptr, nullptr, S, II, H, H, H);
    // 8. down-proj: out += act @ down_w^T  (split-K=4, partials, no atomics)
    w2bf<<<16777216 / 2048, 256, 0, stream>>>(W + 46137344, Wbuf);
    gemm256<float, false, false, true><<<dim3(S / 256, H / 256, 4), 512, 0, stream>>>(
        act, Wbuf, out, nullptr, P_d, S, H, II, II, II / 4);
    reduce_add<3><<<(S * H / 4) / 256, 256, 0, stream>>>(out, P_d);
}

// Round 4
// 865.117 us; speedup vs baseline: 1.0691x; 1.0691x over previous
//
#include <hip/hip_runtime.h>
#include <type_traits>
#include <cstdint>
#include <cstddef>

// ---- types ----
typedef __bf16 bf16x8 __attribute__((ext_vector_type(8)));
typedef float  f32x4  __attribute__((ext_vector_type(4)));
typedef unsigned short u16v4 __attribute__((ext_vector_type(4)));
typedef unsigned short u16v8 __attribute__((ext_vector_type(8)));

#define H    2048
#define NH   16
#define NKV  8
#define HD   128
#define II   8192
#define S    2048

__device__ __forceinline__ unsigned short f2bf(float f) {
    union { float f; unsigned u; } v; v.f = f;
    unsigned r = v.u + 0x7fffu + ((v.u >> 16) & 1u);
    return (unsigned short)(r >> 16);
}
__device__ __forceinline__ float bf2f(unsigned short b) {
    union { unsigned u; float f; } v; v.u = ((unsigned)b) << 16;
    return v.f;
}

// async global->LDS, 16B per lane. LDS dest must be wave-uniform base;
// HW adds lane*16.
__device__ __forceinline__ void async16(const unsigned short* g, const unsigned short* l) {
    __builtin_amdgcn_global_load_lds(
        (const __attribute__((address_space(1))) void*)g,
        (__attribute__((address_space(3))) void*)l, 16, 0, 0);
}

// ---------------- weight fp32 -> bf16 (8 elems/thread) ----------------
__global__ __launch_bounds__(256) void w2bf(const float* __restrict__ src,
                                            unsigned short* __restrict__ dst)
{
    const size_t i = (size_t)blockIdx.x * 256 + threadIdx.x;
    float4 a = ((const float4*)src)[2 * i];
    float4 b = ((const float4*)src)[2 * i + 1];
    u16v8 o;
    o[0] = f2bf(a.x); o[1] = f2bf(a.y); o[2] = f2bf(a.z); o[3] = f2bf(a.w);
    o[4] = f2bf(b.x); o[5] = f2bf(b.y); o[6] = f2bf(b.z); o[7] = f2bf(b.w);
    ((u16v8*)dst)[i] = o;
}

// ---- mlp weights fp32 -> bf16 with up/gate interleave for 256-row B-tiles ----
// src: up [II][H] then gate [II][H].
// dst row p: g=p>>8, r=p&255, half=r>>7 (0=up,1=gate), col c=g*128+(r&127)
// -> each 256-row B-tile g holds up rows c (tile rows 0-127) and gate rows of
//    the SAME c (tile rows 128-255), so wave-cols 0-127=up, 128-255=gate.
__global__ __launch_bounds__(256) void w2bf_mlp256(const float* __restrict__ src,
                                                   unsigned short* __restrict__ dst)
{
    const int p = blockIdx.x;
    const int g = p >> 8, r = p & 255;
    const int half = r >> 7;
    const int c = (g << 7) + (r & 127);
    const float* s = src + ((size_t)half * II + c) * H;
    unsigned short* d = dst + (size_t)p * H;
    const int t = threadIdx.x;
    float4 a = ((const float4*)s)[2 * t];
    float4 b = ((const float4*)s)[2 * t + 1];
    u16v8 o;
    o[0] = f2bf(a.x); o[1] = f2bf(a.y); o[2] = f2bf(a.z); o[3] = f2bf(a.w);
    o[4] = f2bf(b.x); o[5] = f2bf(b.y); o[6] = f2bf(b.z); o[7] = f2bf(b.w);
    *(u16v8*)&d[t * 8] = o;
}

// ---------------- RMSNorm: fp32 in -> bf16 out ----------------
__global__ __launch_bounds__(256) void rmsnorm_kernel(
    const float* __restrict__ x, const float* __restrict__ w,
    unsigned short* __restrict__ out)
{
    __shared__ float red[4];
    const int row = blockIdx.x;
    const int tid = threadIdx.x;
    const float* xr = x + (size_t)row * H;
    float4 v0 = ((const float4*)xr)[tid];
    float4 v1 = ((const float4*)xr)[256 + tid];
    float s = v0.x*v0.x + v0.y*v0.y + v0.z*v0.z + v0.w*v0.w
            + v1.x*v1.x + v1.y*v1.y + v1.z*v1.z + v1.w*v1.w;
    #pragma unroll
    for (int o = 1; o < 64; o <<= 1) s += __shfl_xor(s, o);
    if ((tid & 63) == 0) red[tid >> 6] = s;
    __syncthreads();
    float tot = red[0] + red[1] + red[2] + red[3];
    float rinv = rsqrtf(tot * (1.0f / (float)H) + 1e-6f);
    float4 w0 = ((const float4*)w)[tid];
    float4 w1 = ((const float4*)w)[256 + tid];
    u16v4 o0, o1;
    o0[0] = f2bf(v0.x * w0.x * rinv); o0[1] = f2bf(v0.y * w0.y * rinv);
    o0[2] = f2bf(v0.z * w0.z * rinv); o0[3] = f2bf(v0.w * w0.w * rinv);
    o1[0] = f2bf(v1.x * w1.x * rinv); o1[1] = f2bf(v1.y * w1.y * rinv);
    o1[2] = f2bf(v1.z * w1.z * rinv); o1[3] = f2bf(v1.w * w1.w * rinv);
    unsigned short* orow = out + (size_t)row * H;
    *(u16v4*)&orow[tid * 4]        = o0;
    *(u16v4*)&orow[1024 + tid * 4] = o1;
}

// ---------------- GEMM (m97 structure, kept for QKV / O-proj) ----------------
template<typename OutT, bool ATOMIC, bool SILU, bool SWAP>
__global__ __launch_bounds__(256) void gemm_bf16(
    const unsigned short* __restrict__ A, const unsigned short* __restrict__ B,
    OutT* __restrict__ C, const float* __restrict__ R,
    int M, int N, int K, int lda, int kslice)
{
    __shared__ unsigned short SM[8192];       // As = SM[0..4095], Bs = SM[4096..8191]
    unsigned short* As = SM;
    unsigned short* Bs = SM + 4096;
    const int tid  = threadIdx.x;
    const int wave = tid >> 6, lane = tid & 63;
    const int quad = lane >> 4, l16 = lane & 15;
    const int nt = SWAP ? blockIdx.y : blockIdx.x;
    const int mt = SWAP ? blockIdx.x : blockIdx.y;
    const int m0 = mt * 128, n0 = nt * 128;
    const int wm = (wave >> 1) * 64, wn = (wave & 1) * 64;
    const int kbeg = blockIdx.z * kslice;

    const int sr = lane >> 2;          // row within 16-row group
    const int sc = (lane & 3) * 8;     // col elems 0,8,16,24
    const unsigned short* Ag0 = A + (size_t)(m0 + wave * 16 + sr) * lda + sc + kbeg;
    const unsigned short* Ag1 = Ag0 + (size_t)64 * lda;
    const unsigned short* Bg0 = B + (size_t)(n0 + wave * 16 + sr) * K + sc + kbeg;
    const unsigned short* Bg1 = Bg0 + (size_t)64 * K;
    const unsigned short* Al0 = &As[(wave * 16) * 32];        // wave-uniform bases
    const unsigned short* Al1 = &As[(64 + wave * 16) * 32];
    const unsigned short* Bl0 = &Bs[(wave * 16) * 32];
    const unsigned short* Bl1 = &Bs[(64 + wave * 16) * 32];

    f32x4 acc[4][4] = {};

    for (int k0 = 0; k0 < kslice; k0 += 32) {
        async16(Ag0 + k0, Al0);
        async16(Ag1 + k0, Al1);
        async16(Bg0 + k0, Bl0);
        async16(Bg1 + k0, Bl1);
        __syncthreads();

        bf16x8 af[4], bfm[4];
        #pragma unroll
        for (int i = 0; i < 4; i++)
            af[i] = *(const bf16x8*)&As[(wm + i * 16 + l16) * 32 + quad * 8];
        #pragma unroll
        for (int i = 0; i < 4; i++)
            bfm[i] = *(const bf16x8*)&Bs[(wn + i * 16 + l16) * 32 + quad * 8];
        #pragma unroll
        for (int mi = 0; mi < 4; mi++)
            #pragma unroll
            for (int ni = 0; ni < 4; ni++)
                acc[mi][ni] = __builtin_amdgcn_mfma_f32_16x16x32_bf16(
                    af[mi], bfm[ni], acc[mi][ni], 0, 0, 0);
        __syncthreads();
    }

    #pragma unroll
    for (int mi = 0; mi < 4; mi++) {
        #pragma unroll
        for (int r = 0; r < 4; r++) {
            const int m = m0 + wm + mi * 16 + quad * 4 + r;
            const size_t rowoff = (size_t)m * N;
            #pragma unroll
            for (int ni = 0; ni < 4; ni++) {
                const int n = n0 + wn + ni * 16 + l16;
                float v = acc[mi][ni][r];
                if constexpr (ATOMIC) {
                    if (R != nullptr && blockIdx.z == 0) v += R[rowoff + n];
                    atomicAdd((float*)&C[rowoff + n], v);
                } else if constexpr (std::is_same<OutT, float>::value) {
                    C[rowoff + n] = v;
                } else {
                    C[rowoff + n] = f2bf(v);
                }
            }
        }
    }
}

// ---------------- 256x256 8-phase GEMM (T1+T2+T3+T4+T5, R2 schedule) ----------
// BM=BN=256, BK=64, 512 thr = 8 waves (2M x 4N). Per-wave out 128x64 =
// acc[8][4]. LDS 128 KiB double-buffered; raw s_barrier; counted vmcnt.
//
// R2 DERIVED-WAIT schedule (measured best: 155 us / 37% MfmaUtil on up|gate):
// all 8 loads of tile t+1 issue during t.p0 (4) and t.p1 (4), ordered
// {a0,b0,a1,b1 | a2,b2,a3,b3} where the first 4 cover exactly what t+1.p0
// reads. Waits:
//   t.p0-end vmcnt(4): outstanding = t+1's first 4  => ALL of tile t landed
//                      (covers p1/p2 reads). Window for t's last-4: ~3 phases.
//   t.p3-end vmcnt(4): outstanding = t+1's 8        => t+1's first 4 landed
//                      (covers t+1.p0 reads). Window: ~3 phases.
// Last tile: p0-end vmcnt(0) drains; p3 wait skipped.
// [R3 lesson: deeper B-prefetch (2-tile, 160 KiB LDS, moved waits) = 28% util
//  REGRESSION; B is mostly L2-resident (FETCH=one pass), depth isn't the gap.]
template<typename OutT, bool ATOMIC, bool SILU>
__global__ __launch_bounds__(512, 2) void gemm256(
    const unsigned short* __restrict__ A, const unsigned short* __restrict__ B,
    OutT* __restrict__ C, const float* __restrict__ R,
    int M, int N, int K, int lda, int kslice)
{
    __shared__ unsigned short SM[65536];   // [slot*32768]:  A 16384 | B 16384
    const int tid  = threadIdx.x;
    const int wave = tid >> 6, lane = tid & 63;
    const int quad = lane >> 4, l16 = lane & 15;
    const int wm = wave >> 2, wn = wave & 3;

    // T1: bijective XCD swizzle; M-tile fast so consecutive ids share a B-panel.
    const int nMt = gridDim.x;
    const int nwg = nMt * gridDim.y;
    const int orig = blockIdx.y * nMt + blockIdx.x;
    const int q8 = nwg >> 3, r8 = nwg & 7;
    const int xcd = orig & 7, lid = orig >> 3;
    const int wgid = (xcd < r8 ? xcd * (q8 + 1) : r8 * (q8 + 1) + (xcd - r8) * q8) + lid;
    const int mt = wgid % nMt, ntile = wgid / nMt;
    const int m0 = mt * 256, n0 = ntile * 256;
    const int kbeg = blockIdx.z * kslice;

    // staging: row-group = 8 rows x 64 cols = one wave async16.
    // lane l writes stored block (l&7) of row base+(l>>3); stored = logical ^
    // (row&7), row&7 == l>>3 => source block = (l&7)^(l>>3).
    const int rIn  = lane >> 3;
    const int cBlk = ((lane & 7) ^ rIn) * 8;
    const unsigned short* Ab = A + (size_t)(m0 + rIn) * lda + kbeg + cBlk;
    const unsigned short* Bb = B + (size_t)(n0 + rIn) * K   + kbeg + cBlk;
    // group schedule: union over waves of {ga0,gb0,ga1,gb1} == p0's read set.
    const int ga0 = wave,      ga1 = 16 + wave, ga2 = 8 + wave, ga3 = 24 + wave;
    const int gbB = (wave & 3) + ((wave >> 2) << 4);
    const int gb0 = gbB, gb1 = gbB + 8, gb2 = gbB + 4, gb3 = gbB + 12;

    auto stgA = [&](int g, int kt, int s) {
        async16(Ab + (size_t)g * 8 * lda + kt * 64, &SM[s * 32768 + g * 512]);
    };
    auto stgB = [&](int g, int kt, int s) {
        async16(Bb + (size_t)g * 8 * K + kt * 64, &SM[s * 32768 + 16384 + g * 512]);
    };

    // fragment read addressing (stored block = logical ^ (row&7))
    const int rx   = l16 & 7;
    const int blk0 = (quad ^ rx) * 8;           // ks=0
    const int blk1 = ((4 | quad) ^ rx) * 8;     // ks=1
    const int rowA = (wm * 128 + l16) * 64;
    const int rowB = (wn * 64 + l16) * 64;

    f32x4 acc[8][4] = {};
    const int nkt = kslice >> 6;

    // prologue: tile 0 -> slot 0, order {a0,b0,a1,b1,a2,b2,a3,b3}
    stgA(ga0, 0, 0); stgB(gb0, 0, 0);
    stgA(ga1, 0, 0); stgB(gb1, 0, 0);
    stgA(ga2, 0, 0); stgB(gb2, 0, 0);
    stgA(ga3, 0, 0); stgB(gb3, 0, 0);
    asm volatile("s_waitcnt vmcnt(4)" ::: "memory");   // first half landed
    __builtin_amdgcn_s_barrier();

    for (int t = 0; t < nkt; ++t) {
        const int cur = t & 1, nxt = cur ^ 1;
        const bool more = (t + 1 < nkt);
        const unsigned short* Ac = &SM[cur * 32768];
        const unsigned short* Bc = Ac + 16384;
        bf16x8 af[4][2], bg[4][2];

        // ===== phase 0: read A(mi0-3)+B(ni0-1); stage t+1 first-4; MFMA q(00)
        #pragma unroll
        for (int mi = 0; mi < 4; ++mi) {
            af[mi][0] = *(const bf16x8*)&Ac[rowA + mi * 1024 + blk0];
            af[mi][1] = *(const bf16x8*)&Ac[rowA + mi * 1024 + blk1];
        }
        #pragma unroll
        for (int ni = 0; ni < 2; ++ni) {
            bg[ni][0] = *(const bf16x8*)&Bc[rowB + ni * 1024 + blk0];
            bg[ni][1] = *(const bf16x8*)&Bc[rowB + ni * 1024 + blk1];
        }
        if (more) {
            stgA(ga0, t + 1, nxt); stgB(gb0, t + 1, nxt);
            stgA(ga1, t + 1, nxt); stgB(gb1, t + 1, nxt);
        }
        __builtin_amdgcn_s_barrier();
        asm volatile("s_waitcnt lgkmcnt(0)" ::: "memory");
        __builtin_amdgcn_sched_barrier(0);
        __builtin_amdgcn_s_setprio(1);
        #pragma unroll
        for (int mi = 0; mi < 4; ++mi)
            #pragma unroll
            for (int ni = 0; ni < 2; ++ni) {
                acc[mi][ni] = __builtin_amdgcn_mfma_f32_16x16x32_bf16(af[mi][0], bg[ni][0], acc[mi][ni], 0, 0, 0);
                acc[mi][ni] = __builtin_amdgcn_mfma_f32_16x16x32_bf16(af[mi][1], bg[ni][1], acc[mi][ni], 0, 0, 0);
            }
        __builtin_amdgcn_s_setprio(0);
        if (more) { asm volatile("s_waitcnt vmcnt(4)" ::: "memory"); }
        else      { asm volatile("s_waitcnt vmcnt(0)" ::: "memory"); }
        __builtin_amdgcn_s_barrier();

        // ===== phase 1: read B(ni2-3); stage t+1 last-4; MFMA q(01)
        #pragma unroll
        for (int ni = 2; ni < 4; ++ni) {
            bg[ni][0] = *(const bf16x8*)&Bc[rowB + ni * 1024 + blk0];
            bg[ni][1] = *(const bf16x8*)&Bc[rowB + ni * 1024 + blk1];
        }
        if (more) {
            stgA(ga2, t + 1, nxt); stgB(gb2, t + 1, nxt);
            stgA(ga3, t + 1, nxt); stgB(gb3, t + 1, nxt);
        }
        __builtin_amdgcn_s_barrier();
        asm volatile("s_waitcnt lgkmcnt(0)" ::: "memory");
        __builtin_amdgcn_sched_barrier(0);
        __builtin_amdgcn_s_setprio(1);
        #pragma unroll
        for (int mi = 0; mi < 4; ++mi)
            #pragma unroll
            for (int ni = 2; ni < 4; ++ni) {
                acc[mi][ni] = __builtin_amdgcn_mfma_f32_16x16x32_bf16(af[mi][0], bg[ni][0], acc[mi][ni], 0, 0, 0);
                acc[mi][ni] = __builtin_amdgcn_mfma_f32_16x16x32_bf16(af[mi][1], bg[ni][1], acc[mi][ni], 0, 0, 0);
            }
        __builtin_amdgcn_s_setprio(0);
        __builtin_amdgcn_s_barrier();

        // ===== phase 2: read A(mi4-7); MFMA q(10)
        #pragma unroll
        for (int mi = 0; mi < 4; ++mi) {
            af[mi][0] = *(const bf16x8*)&Ac[rowA + (4 + mi) * 1024 + blk0];
            af[mi][1] = *(const bf16x8*)&Ac[rowA + (4 + mi) * 1024 + blk1];
        }
        __builtin_amdgcn_s_barrier();
        asm volatile("s_waitcnt lgkmcnt(0)" ::: "memory");
        __builtin_amdgcn_sched_barrier(0);
        __builtin_amdgcn_s_setprio(1);
        #pragma unroll
        for (int mi = 0; mi < 4; ++mi)
            #pragma unroll
            for (int ni = 0; ni < 2; ++ni) {
                acc[4 + mi][ni] = __builtin_amdgcn_mfma_f32_16x16x32_bf16(af[mi][0], bg[ni][0], acc[4 + mi][ni], 0, 0, 0);
                acc[4 + mi][ni] = __builtin_amdgcn_mfma_f32_16x16x32_bf16(af[mi][1], bg[ni][1], acc[4 + mi][ni], 0, 0, 0);
            }
        __builtin_amdgcn_s_setprio(0);
        __builtin_amdgcn_s_barrier();

        // ===== phase 3: MFMA q(11); vmcnt(4) -> t+1 first half landed
        __builtin_amdgcn_s_setprio(1);
        #pragma unroll
        for (int mi = 0; mi < 4; ++mi)
            #pragma unroll
            for (int ni = 2; ni < 4; ++ni) {
                acc[4 + mi][ni] = __builtin_amdgcn_mfma_f32_16x16x32_bf16(af[mi][0], bg[ni][0], acc[4 + mi][ni], 0, 0, 0);
                acc[4 + mi][ni] = __builtin_amdgcn_mfma_f32_16x16x32_bf16(af[mi][1], bg[ni][1], acc[4 + mi][ni], 0, 0, 0);
            }
        __builtin_amdgcn_s_setprio(0);
        if (more) { asm volatile("s_waitcnt vmcnt(4)" ::: "memory"); }
        __builtin_amdgcn_s_barrier();
    }

    if constexpr (SILU) {
        // B-tile rows 0-127 = up (wn 0,1), 128-255 = gate (wn 2,3).
        // Gate waves hand accs to up waves through the dead stage LDS;
        // stride 132 (not 128) spreads the 4 quads over banks.
        unsigned short* Ex = SM;                      // 256*132*2 B = 66 KiB
        if (wn >= 2) {
            #pragma unroll
            for (int mi = 0; mi < 8; ++mi)
                #pragma unroll
                for (int r = 0; r < 4; ++r) {
                    const int rl = wm * 128 + mi * 16 + quad * 4 + r;
                    #pragma unroll
                    for (int ni = 0; ni < 4; ++ni)
                        Ex[rl * 132 + (wn - 2) * 64 + ni * 16 + l16] = f2bf(acc[mi][ni][r]);
                }
        }
        __builtin_amdgcn_s_barrier();
        if (wn < 2) {
            #pragma unroll
            for (int mi = 0; mi < 8; ++mi)
                #pragma unroll
                for (int r = 0; r < 4; ++r) {
                    const int rl = wm * 128 + mi * 16 + quad * 4 + r;
                    const size_t rowoff = (size_t)(m0 + rl) * N;
                    #pragma unroll
                    for (int ni = 0; ni < 4; ++ni) {
                        const int cl = wn * 64 + ni * 16 + l16;
                        float g = bf2f(Ex[rl * 132 + cl]);
                        float u = acc[mi][ni][r];
                        float sig = 1.0f / (1.0f + exp2f(-g * 1.4426950408889634f));
                        C[rowoff + (n0 >> 1) + cl] = f2bf(g * sig * u);
                    }
                }
        }
        return;
    }

    #pragma unroll
    for (int mi = 0; mi < 8; ++mi) {
        #pragma unroll
        for (int r = 0; r < 4; ++r) {
            const int m = m0 + wm * 128 + mi * 16 + quad * 4 + r;
            const size_t rowoff = (size_t)m * N;
            #pragma unroll
            for (int ni = 0; ni < 4; ++ni) {
                const int n = n0 + wn * 64 + ni * 16 + l16;
                float v = acc[mi][ni][r];
                if constexpr (ATOMIC) {
                    if (R != nullptr && blockIdx.z == 0) v += R[rowoff + n];
                    atomicAdd((float*)&C[rowoff + n], v);
                } else if constexpr (std::is_same<OutT, float>::value) {
                    C[rowoff + n] = v;
                } else {
                    C[rowoff + n] = f2bf(v);
                }
            }
        }
    }
}

// ---------------- RoPE prep: qkv bf16 [S,4096] -> q_r [NH,S,HD], k_r [NKV,S,HD] ----
__global__ __launch_bounds__(256) void rope_prep(
    const unsigned short* __restrict__ qkv, const float* __restrict__ cosp,
    const float* __restrict__ sinp,
    unsigned short* __restrict__ q_r, unsigned short* __restrict__ k_r)
{
    const int s = blockIdx.x;
    const int tid = threadIdx.x;
    const unsigned short* row = qkv + (size_t)s * 4096;
    #pragma unroll
    for (int j = 0; j < 12; j++) {          // 3072 = q(2048) + k(1024)
        int e = j * 256 + tid;
        int head = e >> 7, hd = e & 127;
        float v = bf2f(row[e]);
        float part = (hd < 64) ? -bf2f(row[e + 64]) : bf2f(row[e - 64]);
        float c  = cosp[s * HD + hd];
        float sn = sinp[s * HD + hd];
        unsigned short ob = f2bf(v * c + part * sn);
        if (head < NH) q_r[((size_t)head * S + s) * HD + hd] = ob;
        else           k_r[((size_t)(head - NH) * S + s) * HD + hd] = ob;
    }
}

// ---------------- V transpose: qkv bf16 cols 3072..4095 -> v_t TILED bf16 ----------
// v_t layout: [NKV][S/32 key-tiles][HD=128][32 keys]  (each tile = contiguous 8 KB)
__global__ __launch_bounds__(256) void v_trans(
    const unsigned short* __restrict__ qkv, unsigned short* __restrict__ v_t)
{
    __shared__ unsigned short t[128][66];
    const int s0 = blockIdx.x * 64;
    const int kv = blockIdx.y;
    const int tid = threadIdx.x;
    const unsigned short* base = qkv + 3072 + kv * HD;
    #pragma unroll
    for (int i = 0; i < 4; i++) {
        int idx = i * 256 + tid;            // one u16v8 each, 1024 total
        int s_l = idx >> 4;
        int hd8 = (idx & 15) * 8;
        u16v8 v = *(const u16v8*)(base + (size_t)(s0 + s_l) * 4096 + hd8);
        #pragma unroll
        for (int j = 0; j < 8; j++) t[hd8 + j][s_l] = v[j];
    }
    __syncthreads();
    #pragma unroll
    for (int i = 0; i < 8; i++) {
        int idx = i * 256 + tid;            // 2048 u16v4 chunks
        int d  = idx >> 4;                  // 0..127
        int rm = idx & 15;
        int hh = rm >> 3;                   // key-tile half 0/1
        int s4 = (rm & 7) * 4;              // 0..28 within tile
        u16v4 o;
        o[0] = t[d][hh * 32 + s4];     o[1] = t[d][hh * 32 + s4 + 1];
        o[2] = t[d][hh * 32 + s4 + 2]; o[3] = t[d][hh * 32 + s4 + 3];
        size_t tile = (size_t)kv * (S / 32) + (s0 >> 5) + hh;
        *(u16v4*)&v_t[(tile * 128 + d) * 32 + s4] = o;
    }
}

// ---------------- Flash attention (LDS-staged K/V, swizzled) ----------------
__global__ __launch_bounds__(256) void attn_kernel(
    const unsigned short* __restrict__ q_r, const unsigned short* __restrict__ k_r,
    const unsigned short* __restrict__ v_t, unsigned short* __restrict__ out)
{
    __shared__ unsigned short Ks[32 * 128];
    __shared__ unsigned short Vs[144 * 32];
    __shared__ unsigned short P[4][16][40];
    const int h = blockIdx.y, kv = h >> 1;
    const int qb0 = blockIdx.x * 64;
    const int tid = threadIdx.x;
    const int wave = tid >> 6, lane = tid & 63, quad = lane >> 4, l16 = lane & 15;
    const int qb = qb0 + wave * 16;
    const unsigned short* Q  = q_r + (size_t)h * S * HD;
    const unsigned short* K  = k_r + (size_t)kv * S * HD;
    const unsigned short* Vh = v_t + (size_t)kv * (S / 32) * (128 * 32);

    // ones rows for the l-sum tile (rows 129..143 zero)
    {
        int e0 = tid * 2;
        Vs[128 * 32 + e0]     = (e0     < 32) ? (unsigned short)0x3F80 : (unsigned short)0;
        Vs[128 * 32 + e0 + 1] = (e0 + 1 < 32) ? (unsigned short)0x3F80 : (unsigned short)0;
    }

    bf16x8 aq[4];
    #pragma unroll
    for (int t = 0; t < 4; t++)
        aq[t] = *(const bf16x8*)&Q[(size_t)(qb + l16) * HD + t * 32 + quad * 8];

    f32x4 o[9] = {};                       // o[8] = row-sum accumulator (l)
    float m_i[4] = { -__builtin_inff(), -__builtin_inff(), -__builtin_inff(), -__builtin_inff() };
    const float SCL = 0.08838834764831845f * 1.4426950408889634f;  // 1/sqrt(HD)*log2(e)
    const int nk = (qb0 >> 5) + 2;

    const int kr  = (lane >> 4);           // K: row within 4-row issue group
    const int kbl = lane & 15;             // K: 16B block within 256B row
    const int vr  = (lane >> 2);           // V: row within 16-row issue group
    const int vbl = lane & 3;              // V: 16B block within 64B row

    for (int kb = 0; kb < nk; kb++) {
        const int kbase = kb * 32;
        const unsigned short* Ktile = K + (size_t)kbase * HD;
        const unsigned short* Vtile = Vh + (size_t)kb * (128 * 32);
        #pragma unroll
        for (int e = 0; e < 2; e++) {
            int r = wave * 8 + e * 4 + kr;
            async16(Ktile + r * 128 + ((kbl ^ (r & 15)) * 8), &Ks[(wave * 8 + e * 4) * 128]);
        }
        #pragma unroll
        for (int e = 0; e < 2; e++) {
            int d = wave * 32 + e * 16 + vr;
            async16(Vtile + d * 32 + ((vbl ^ (d & 3)) * 8), &Vs[(wave * 32 + e * 16) * 32]);
        }
        __syncthreads();   // vmcnt(0) drain: tiles landed

        if (kbase <= qb + 15) {
            f32x4 s0 = {0.f, 0.f, 0.f, 0.f}, s1 = {0.f, 0.f, 0.f, 0.f};
            #pragma unroll
            for (int t = 0; t < 4; t++) {
                int b = t * 4 + quad;
                bf16x8 b0 = *(const bf16x8*)&Ks[l16 * 128 + ((b ^ l16) * 8)];
                bf16x8 b1 = *(const bf16x8*)&Ks[(16 + l16) * 128 + ((b ^ l16) * 8)];
                s0 = __builtin_amdgcn_mfma_f32_16x16x32_bf16(aq[t], b0, s0, 0, 0, 0);
                s1 = __builtin_amdgcn_mfma_f32_16x16x32_bf16(aq[t], b1, s1, 0, 0, 0);
            }
            float alpha[4];
            #pragma unroll
            for (int r = 0; r < 4; r++) {
                const int q = qb + quad * 4 + r;
                float v0 = (kbase + l16      <= q) ? s0[r] * SCL : -__builtin_inff();
                float v1 = (kbase + 16 + l16 <= q) ? s1[r] * SCL : -__builtin_inff();
                float mx = fmaxf(v0, v1);
                #pragma unroll
                for (int d = 1; d < 16; d <<= 1) mx = fmaxf(mx, __shfl_xor(mx, d));
                float nm = fmaxf(m_i[r], mx);
                alpha[r] = exp2f(m_i[r] - nm);
                m_i[r] = nm;
                s0[r] = exp2f(v0 - nm);
                s1[r] = exp2f(v1 - nm);
            }
            #pragma unroll
            for (int ni = 0; ni < 9; ni++)
                #pragma unroll
                for (int r = 0; r < 4; r++) o[ni][r] *= alpha[r];
            #pragma unroll
            for (int r = 0; r < 4; r++) {
                P[wave][quad * 4 + r][l16]      = f2bf(s0[r]);
                P[wave][quad * 4 + r][16 + l16] = f2bf(s1[r]);
            }
            asm volatile("s_waitcnt lgkmcnt(0)" ::: "memory");
            bf16x8 ap = *(const bf16x8*)&P[wave][l16][quad * 8];
            #pragma unroll
            for (int ni = 0; ni < 9; ni++) {
                int d = ni * 16 + l16;
                bf16x8 bv = *(const bf16x8*)&Vs[d * 32 + ((quad ^ (d & 3)) * 8)];
                o[ni] = __builtin_amdgcn_mfma_f32_16x16x32_bf16(ap, bv, o[ni], 0, 0, 0);
            }
        }
        __syncthreads();   // all waves done reading before next tile staged
    }
    #pragma unroll
    for (int r = 0; r < 4; r++) {
        float lsum = __shfl(o[8][r], quad * 16);   // l lives in lane (l16=0, quad)
        const float inv = 1.0f / lsum;
        const int qrow = qb + quad * 4 + r;
        #pragma unroll
        for (int ni = 0; ni < 8; ni++)
            out[(size_t)qrow * (NH * HD) + h * HD + ni * 16 + l16] = f2bf(o[ni][r] * inv);
    }
}

// ---------------- launch ----------------
extern "C" void kernel_launch(void* const* d_in, const int* in_sizes, int n_in,
                              void* d_out, int out_size, void* d_ws, size_t ws_size,
                              hipStream_t stream) {
    const float* hs   = (const float*)d_in[0];   // [1,S,H] fp32
    const float* W    = (const float*)d_in[1];   // flat weights fp32
    const float* ln1  = (const float*)d_in[2];
    const float* ln2  = (const float*)d_in[3];
    const float* cosp = (const float*)d_in[4];   // [S,HD]
    const float* sinp = (const float*)d_in[5];
    float* out = (float*)d_out;                  // [S,H] fp32
    char* ws = (char*)d_ws;

    unsigned short* Wbuf   = (unsigned short*)(ws + 0);                  // 64 MiB staged bf16 weights
    unsigned short* x_norm = (unsigned short*)(ws + (64ull  << 20));     // 8 MiB
    unsigned short* qkv    = (unsigned short*)(ws + (72ull  << 20));     // 16 MiB bf16
    unsigned short* act    = (unsigned short*)(ws + (72ull  << 20));     // 32 MiB bf16 (reuses qkv, dead)
    unsigned short* q_r    = (unsigned short*)(ws + (104ull << 20));     // 8 MiB
    unsigned short* k_r    = (unsigned short*)(ws + (112ull << 20));     // 4 MiB
    unsigned short* v_t    = (unsigned short*)(ws + (116ull << 20));     // 4 MiB (tiled)
    unsigned short* attn_o = (unsigned short*)(ws + (120ull << 20));     // 8 MiB

    // 1. stage qkv weights -> bf16 ; input RMSNorm
    w2bf<<<8388608 / 2048, 256, 0, stream>>>(W, Wbuf);
    rmsnorm_kernel<<<S, 256, 0, stream>>>(hs, ln1, x_norm);
    // 2. fused QKV GEMM -> qkv bf16 [S,4096]
    gemm_bf16<unsigned short, false, false, true><<<dim3(S / 128, 4096 / 128, 1), 256, 0, stream>>>(
        x_norm, Wbuf, qkv, nullptr, S, 4096, H, H, H);
    // 3. RoPE + layouts
    rope_prep<<<S, 256, 0, stream>>>(qkv, cosp, sinp, q_r, k_r);
    v_trans<<<dim3(S / 64, NKV), 256, 0, stream>>>(qkv, v_t);
    // 4. causal flash attention
    attn_kernel<<<dim3(S / 64, NH), 256, 0, stream>>>(q_r, k_r, v_t, attn_o);
    // 5. O-proj: out = hs + attn_o @ o_w^T  (memset + split-K=2 atomic, z0 adds hs)
    w2bf<<<4194304 / 2048, 256, 0, stream>>>(W + 8388608, Wbuf);
    hipMemsetAsync(out, 0, (size_t)S * H * sizeof(float), stream);
    gemm_bf16<float, true, false, false><<<dim3(H / 128, S / 128, 2), 256, 0, stream>>>(
        attn_o, Wbuf, out, hs, S, H, H, H, H / 2);
    // 6. post RMSNorm
    rmsnorm_kernel<<<S, 256, 0, stream>>>(out, ln2, x_norm);
    // 7. fused up|gate GEMM + SiLU epilogue -> act bf16 [S, II]  (256^2, R2 sched)
    w2bf_mlp256<<<2 * II, 256, 0, stream>>>(W + 12582912, Wbuf);
    gemm256<unsigned short, false, true><<<dim3(S / 256, (2 * II) / 256, 1), 512, 0, stream>>>(
        x_norm, Wbuf, act, nullptr, S, II, H, H, H);
    // 8. down-proj: out += act @ down_w^T  (split-K=4 atomic; residual already in out)
    w2bf<<<16777216 / 2048, 256, 0, stream>>>(W + 46137344, Wbuf);
    gemm256<float, true, false><<<dim3(S / 256, H / 256, 4), 512, 0, stream>>>(
        act, Wbuf, out, nullptr, S, H, II, II, II / 4);
}

// Round 5
// 864.751 us; speedup vs baseline: 1.0695x; 1.0004x over previous
//
#include <hip/hip_runtime.h>
#include <type_traits>
#include <cstdint>
#include <cstddef>

// ---- types ----
typedef __bf16 bf16x8 __attribute__((ext_vector_type(8)));
typedef float  f32x4  __attribute__((ext_vector_type(4)));
typedef unsigned short u16v4 __attribute__((ext_vector_type(4)));
typedef unsigned short u16v8 __attribute__((ext_vector_type(8)));

#define H    2048
#define NH   16
#define NKV  8
#define HD   128
#define II   8192
#define S    2048

__device__ __forceinline__ unsigned short f2bf(float f) {
    union { float f; unsigned u; } v; v.f = f;
    unsigned r = v.u + 0x7fffu + ((v.u >> 16) & 1u);
    return (unsigned short)(r >> 16);
}
__device__ __forceinline__ float bf2f(unsigned short b) {
    union { unsigned u; float f; } v; v.u = ((unsigned)b) << 16;
    return v.f;
}

// async global->LDS, 16B per lane. LDS dest must be wave-uniform base;
// HW adds lane*16.
__device__ __forceinline__ void async16(const unsigned short* g, const unsigned short* l) {
    __builtin_amdgcn_global_load_lds(
        (const __attribute__((address_space(1))) void*)g,
        (__attribute__((address_space(3))) void*)l, 16, 0, 0);
}

// ---------------- weight fp32 -> bf16 (8 elems/thread) ----------------
__global__ __launch_bounds__(256) void w2bf(const float* __restrict__ src,
                                            unsigned short* __restrict__ dst)
{
    const size_t i = (size_t)blockIdx.x * 256 + threadIdx.x;
    float4 a = ((const float4*)src)[2 * i];
    float4 b = ((const float4*)src)[2 * i + 1];
    u16v8 o;
    o[0] = f2bf(a.x); o[1] = f2bf(a.y); o[2] = f2bf(a.z); o[3] = f2bf(a.w);
    o[4] = f2bf(b.x); o[5] = f2bf(b.y); o[6] = f2bf(b.z); o[7] = f2bf(b.w);
    ((u16v8*)dst)[i] = o;
}

// ---- mlp weights fp32 -> bf16 with up/gate interleave for 256-row B-tiles ----
// src: up [II][H] then gate [II][H].
// dst row p: g=p>>8, r=p&255, half=r>>7 (0=up,1=gate), col c=g*128+(r&127)
// -> each 256-row B-tile g holds up rows c (tile rows 0-127) and gate rows of
//    the SAME c (tile rows 128-255), so wave-cols 0-127=up, 128-255=gate.
__global__ __launch_bounds__(256) void w2bf_mlp256(const float* __restrict__ src,
                                                   unsigned short* __restrict__ dst)
{
    const int p = blockIdx.x;
    const int g = p >> 8, r = p & 255;
    const int half = r >> 7;
    const int c = (g << 7) + (r & 127);
    const float* s = src + ((size_t)half * II + c) * H;
    unsigned short* d = dst + (size_t)p * H;
    const int t = threadIdx.x;
    float4 a = ((const float4*)s)[2 * t];
    float4 b = ((const float4*)s)[2 * t + 1];
    u16v8 o;
    o[0] = f2bf(a.x); o[1] = f2bf(a.y); o[2] = f2bf(a.z); o[3] = f2bf(a.w);
    o[4] = f2bf(b.x); o[5] = f2bf(b.y); o[6] = f2bf(b.z); o[7] = f2bf(b.w);
    *(u16v8*)&d[t * 8] = o;
}

// ---------------- RMSNorm: fp32 in -> bf16 out ----------------
__global__ __launch_bounds__(256) void rmsnorm_kernel(
    const float* __restrict__ x, const float* __restrict__ w,
    unsigned short* __restrict__ out)
{
    __shared__ float red[4];
    const int row = blockIdx.x;
    const int tid = threadIdx.x;
    const float* xr = x + (size_t)row * H;
    float4 v0 = ((const float4*)xr)[tid];
    float4 v1 = ((const float4*)xr)[256 + tid];
    float s = v0.x*v0.x + v0.y*v0.y + v0.z*v0.z + v0.w*v0.w
            + v1.x*v1.x + v1.y*v1.y + v1.z*v1.z + v1.w*v1.w;
    #pragma unroll
    for (int o = 1; o < 64; o <<= 1) s += __shfl_xor(s, o);
    if ((tid & 63) == 0) red[tid >> 6] = s;
    __syncthreads();
    float tot = red[0] + red[1] + red[2] + red[3];
    float rinv = rsqrtf(tot * (1.0f / (float)H) + 1e-6f);
    float4 w0 = ((const float4*)w)[tid];
    float4 w1 = ((const float4*)w)[256 + tid];
    u16v4 o0, o1;
    o0[0] = f2bf(v0.x * w0.x * rinv); o0[1] = f2bf(v0.y * w0.y * rinv);
    o0[2] = f2bf(v0.z * w0.z * rinv); o0[3] = f2bf(v0.w * w0.w * rinv);
    o1[0] = f2bf(v1.x * w1.x * rinv); o1[1] = f2bf(v1.y * w1.y * rinv);
    o1[2] = f2bf(v1.z * w1.z * rinv); o1[3] = f2bf(v1.w * w1.w * rinv);
    unsigned short* orow = out + (size_t)row * H;
    *(u16v4*)&orow[tid * 4]        = o0;
    *(u16v4*)&orow[1024 + tid * 4] = o1;
}

// ---------------- GEMM (m97 structure, kept for QKV / O-proj) ----------------
// float non-atomic path: C = (R? R : 0) + v  (fused residual, plain store)
template<typename OutT, bool ATOMIC, bool SILU, bool SWAP>
__global__ __launch_bounds__(256) void gemm_bf16(
    const unsigned short* __restrict__ A, const unsigned short* __restrict__ B,
    OutT* __restrict__ C, const float* __restrict__ R,
    int M, int N, int K, int lda, int kslice)
{
    __shared__ unsigned short SM[8192];       // As = SM[0..4095], Bs = SM[4096..8191]
    unsigned short* As = SM;
    unsigned short* Bs = SM + 4096;
    const int tid  = threadIdx.x;
    const int wave = tid >> 6, lane = tid & 63;
    const int quad = lane >> 4, l16 = lane & 15;
    const int nt = SWAP ? blockIdx.y : blockIdx.x;
    const int mt = SWAP ? blockIdx.x : blockIdx.y;
    const int m0 = mt * 128, n0 = nt * 128;
    const int wm = (wave >> 1) * 64, wn = (wave & 1) * 64;
    const int kbeg = blockIdx.z * kslice;

    const int sr = lane >> 2;          // row within 16-row group
    const int sc = (lane & 3) * 8;     // col elems 0,8,16,24
    const unsigned short* Ag0 = A + (size_t)(m0 + wave * 16 + sr) * lda + sc + kbeg;
    const unsigned short* Ag1 = Ag0 + (size_t)64 * lda;
    const unsigned short* Bg0 = B + (size_t)(n0 + wave * 16 + sr) * K + sc + kbeg;
    const unsigned short* Bg1 = Bg0 + (size_t)64 * K;
    const unsigned short* Al0 = &As[(wave * 16) * 32];        // wave-uniform bases
    const unsigned short* Al1 = &As[(64 + wave * 16) * 32];
    const unsigned short* Bl0 = &Bs[(wave * 16) * 32];
    const unsigned short* Bl1 = &Bs[(64 + wave * 16) * 32];

    f32x4 acc[4][4] = {};

    for (int k0 = 0; k0 < kslice; k0 += 32) {
        async16(Ag0 + k0, Al0);
        async16(Ag1 + k0, Al1);
        async16(Bg0 + k0, Bl0);
        async16(Bg1 + k0, Bl1);
        __syncthreads();

        bf16x8 af[4], bfm[4];
        #pragma unroll
        for (int i = 0; i < 4; i++)
            af[i] = *(const bf16x8*)&As[(wm + i * 16 + l16) * 32 + quad * 8];
        #pragma unroll
        for (int i = 0; i < 4; i++)
            bfm[i] = *(const bf16x8*)&Bs[(wn + i * 16 + l16) * 32 + quad * 8];
        #pragma unroll
        for (int mi = 0; mi < 4; mi++)
            #pragma unroll
            for (int ni = 0; ni < 4; ni++)
                acc[mi][ni] = __builtin_amdgcn_mfma_f32_16x16x32_bf16(
                    af[mi], bfm[ni], acc[mi][ni], 0, 0, 0);
        __syncthreads();
    }

    #pragma unroll
    for (int mi = 0; mi < 4; mi++) {
        #pragma unroll
        for (int r = 0; r < 4; r++) {
            const int m = m0 + wm + mi * 16 + quad * 4 + r;
            const size_t rowoff = (size_t)m * N;
            #pragma unroll
            for (int ni = 0; ni < 4; ni++) {
                const int n = n0 + wn + ni * 16 + l16;
                float v = acc[mi][ni][r];
                if constexpr (ATOMIC) {
                    if (R != nullptr && blockIdx.z == 0) v += R[rowoff + n];
                    atomicAdd((float*)&C[rowoff + n], v);
                } else if constexpr (std::is_same<OutT, float>::value) {
                    if (R != nullptr) v += R[rowoff + n];
                    C[rowoff + n] = v;
                } else {
                    C[rowoff + n] = f2bf(v);
                }
            }
        }
    }
}

// ---------------- 256x256 2-PHASE GEMM (R5: halved sync count) ----------------
// BM=BN=256, BK=64, 512 thr = 8 waves (2M x 4N), acc[8][4].
// LDS 128 KiB double-buffered (2 slots x [A 16K | B 16K]); swizzle unchanged.
//
// R5 CHANGE (mechanism: stall-EVENT count, not wait ages): 2 phases per
// K-tile, 32 MFMA per cluster -> 4 barriers + 2 lgkm drains per tile
// (was 8 + 4). [R1-R4 lesson: three 4-phase wait-schedule variants all
// land 155-208 us with cross-session noise +-25%; both pipes idle =>
// stall-bound; the shared constant was sync frequency.]
//
// Stage batches per tile t (issued for t+1):
//   batch0 (p0, 6 loads) = A all 4 groups + Bset0 {gb0,gb1}
//     -> exactly what t+1.p0 ds_reads (A mi0-7 + B ni0-1)
//   batch1 (p1, 2 loads) = Bset1 {gb2,gb3}  (B ni2-3, read t+1.p1)
// Queue trace (steady):
//   t.p0-end: outstanding [batch1(t)=2, batch0(t+1)=6] -> vmcnt(6) forces
//     batch1(t) (age 2 phases) before p1 reads it.
//   t.p1-end: outstanding [batch0(t+1)=6, batch1(t+1)=2] -> vmcnt(2) forces
//     batch0(t+1) (age 1 long-phase; A is L2-resident, Bset0 HBM-cold only
//     for 1-in-8 blocks) before t+1.p0 reads it.
// Tail: t=nkt-1: p0-end vmcnt(0); p1-end no wait.
// VGPR: af[8][2]+bg[2][2]+acc[8][4] ~= 208+addr (~235). If this spills
// (numRegs>256) the experiment is void -> check VGPR_Count.
template<typename OutT, bool ATOMIC, bool SILU>
__global__ __launch_bounds__(512, 2) void gemm256(
    const unsigned short* __restrict__ A, const unsigned short* __restrict__ B,
    OutT* __restrict__ C, const float* __restrict__ R,
    int M, int N, int K, int lda, int kslice)
{
    __shared__ unsigned short SM[65536];   // [slot*32768]:  A 16384 | B 16384
    const int tid  = threadIdx.x;
    const int wave = tid >> 6, lane = tid & 63;
    const int quad = lane >> 4, l16 = lane & 15;
    const int wm = wave >> 2, wn = wave & 3;

    // T1: bijective XCD swizzle; M-tile fast so consecutive ids share a B-panel.
    const int nMt = gridDim.x;
    const int nwg = nMt * gridDim.y;
    const int orig = blockIdx.y * nMt + blockIdx.x;
    const int q8 = nwg >> 3, r8 = nwg & 7;
    const int xcd = orig & 7, lid = orig >> 3;
    const int wgid = (xcd < r8 ? xcd * (q8 + 1) : r8 * (q8 + 1) + (xcd - r8) * q8) + lid;
    const int mt = wgid % nMt, ntile = wgid / nMt;
    const int m0 = mt * 256, n0 = ntile * 256;
    const int kbeg = blockIdx.z * kslice;

    // staging: row-group = 8 rows x 64 cols = one wave async16.
    // lane l writes stored block (l&7) of row base+(l>>3); stored = logical ^
    // (row&7), row&7 == l>>3 => source block = (l&7)^(l>>3).
    const int rIn  = lane >> 3;
    const int cBlk = ((lane & 7) ^ rIn) * 8;
    const unsigned short* Ab = A + (size_t)(m0 + rIn) * lda + kbeg + cBlk;
    const unsigned short* Bb = B + (size_t)(n0 + rIn) * K   + kbeg + cBlk;
    const int ga0 = wave,      ga1 = 16 + wave, ga2 = 8 + wave, ga3 = 24 + wave;
    const int gbB = (wave & 3) + ((wave >> 2) << 4);
    const int gb0 = gbB, gb1 = gbB + 8;            // Bset0 (rows 0-31,64-95,128-159,192-223)
    const int gb2 = gbB + 4, gb3 = gbB + 12;       // Bset1

    auto stgA = [&](int g, int kt, int s) {
        async16(Ab + (size_t)g * 8 * lda + kt * 64, &SM[s * 32768 + g * 512]);
    };
    auto stgB = [&](int g, int kt, int s) {
        async16(Bb + (size_t)g * 8 * K + kt * 64, &SM[s * 32768 + 16384 + g * 512]);
    };

    // fragment read addressing (stored block = logical ^ (row&7))
    const int rx   = l16 & 7;
    const int blk0 = (quad ^ rx) * 8;           // ks=0
    const int blk1 = ((4 | quad) ^ rx) * 8;     // ks=1
    const int rowA = (wm * 128 + l16) * 64;
    const int rowB = (wn * 64 + l16) * 64;

    f32x4 acc[8][4] = {};
    const int nkt = kslice >> 6;

    // prologue: tile 0 -> slot 0; batch0 (6) then batch1 (2); wait batch0.
    stgA(ga0, 0, 0); stgA(ga1, 0, 0); stgA(ga2, 0, 0); stgA(ga3, 0, 0);
    stgB(gb0, 0, 0); stgB(gb1, 0, 0);
    stgB(gb2, 0, 0); stgB(gb3, 0, 0);
    asm volatile("s_waitcnt vmcnt(2)" ::: "memory");
    __builtin_amdgcn_s_barrier();

    for (int t = 0; t < nkt; ++t) {
        const int cur = t & 1, nxt = cur ^ 1;
        const bool more = (t + 1 < nkt);
        const unsigned short* Ac = &SM[cur * 32768];
        const unsigned short* Bc = Ac + 16384;
        bf16x8 af[8][2], bg[2][2];

        // ===== phase 0: read A(mi0-7)+B(ni0-1); stage batch0(t+1); MFMA 32 (ni0-1)
        #pragma unroll
        for (int mi = 0; mi < 8; ++mi) {
            af[mi][0] = *(const bf16x8*)&Ac[rowA + mi * 1024 + blk0];
            af[mi][1] = *(const bf16x8*)&Ac[rowA + mi * 1024 + blk1];
        }
        #pragma unroll
        for (int ni = 0; ni < 2; ++ni) {
            bg[ni][0] = *(const bf16x8*)&Bc[rowB + ni * 1024 + blk0];
            bg[ni][1] = *(const bf16x8*)&Bc[rowB + ni * 1024 + blk1];
        }
        if (more) {
            stgA(ga0, t + 1, nxt); stgA(ga1, t + 1, nxt);
            stgA(ga2, t + 1, nxt); stgA(ga3, t + 1, nxt);
            stgB(gb0, t + 1, nxt); stgB(gb1, t + 1, nxt);
        }
        __builtin_amdgcn_s_barrier();
        asm volatile("s_waitcnt lgkmcnt(0)" ::: "memory");
        __builtin_amdgcn_sched_barrier(0);
        __builtin_amdgcn_s_setprio(1);
        #pragma unroll
        for (int mi = 0; mi < 8; ++mi)
            #pragma unroll
            for (int ni = 0; ni < 2; ++ni) {
                acc[mi][ni] = __builtin_amdgcn_mfma_f32_16x16x32_bf16(af[mi][0], bg[ni][0], acc[mi][ni], 0, 0, 0);
                acc[mi][ni] = __builtin_amdgcn_mfma_f32_16x16x32_bf16(af[mi][1], bg[ni][1], acc[mi][ni], 0, 0, 0);
            }
        __builtin_amdgcn_s_setprio(0);
        if (more) { asm volatile("s_waitcnt vmcnt(6)" ::: "memory"); }
        else      { asm volatile("s_waitcnt vmcnt(0)" ::: "memory"); }
        __builtin_amdgcn_s_barrier();

        // ===== phase 1: read B(ni2-3); stage batch1(t+1); MFMA 32 (ni2-3)
        #pragma unroll
        for (int ni = 0; ni < 2; ++ni) {
            bg[ni][0] = *(const bf16x8*)&Bc[rowB + (2 + ni) * 1024 + blk0];
            bg[ni][1] = *(const bf16x8*)&Bc[rowB + (2 + ni) * 1024 + blk1];
        }
        if (more) {
            stgB(gb2, t + 1, nxt); stgB(gb3, t + 1, nxt);
        }
        __builtin_amdgcn_s_barrier();
        asm volatile("s_waitcnt lgkmcnt(0)" ::: "memory");
        __builtin_amdgcn_sched_barrier(0);
        __builtin_amdgcn_s_setprio(1);
        #pragma unroll
        for (int mi = 0; mi < 8; ++mi)
            #pragma unroll
            for (int ni = 0; ni < 2; ++ni) {
                acc[mi][2 + ni] = __builtin_amdgcn_mfma_f32_16x16x32_bf16(af[mi][0], bg[ni][0], acc[mi][2 + ni], 0, 0, 0);
                acc[mi][2 + ni] = __builtin_amdgcn_mfma_f32_16x16x32_bf16(af[mi][1], bg[ni][1], acc[mi][2 + ni], 0, 0, 0);
            }
        __builtin_amdgcn_s_setprio(0);
        if (more) { asm volatile("s_waitcnt vmcnt(2)" ::: "memory"); }
        __builtin_amdgcn_s_barrier();
    }

    if constexpr (SILU) {
        // B-tile rows 0-127 = up (wn 0,1), 128-255 = gate (wn 2,3).
        // Gate waves hand accs to up waves through the dead stage LDS;
        // stride 132 (not 128) spreads the 4 quads over banks.
        unsigned short* Ex = SM;                      // 256*132*2 B = 66 KiB
        if (wn >= 2) {
            #pragma unroll
            for (int mi = 0; mi < 8; ++mi)
                #pragma unroll
                for (int r = 0; r < 4; ++r) {
                    const int rl = wm * 128 + mi * 16 + quad * 4 + r;
                    #pragma unroll
                    for (int ni = 0; ni < 4; ++ni)
                        Ex[rl * 132 + (wn - 2) * 64 + ni * 16 + l16] = f2bf(acc[mi][ni][r]);
                }
        }
        __builtin_amdgcn_s_barrier();
        if (wn < 2) {
            #pragma unroll
            for (int mi = 0; mi < 8; ++mi)
                #pragma unroll
                for (int r = 0; r < 4; ++r) {
                    const int rl = wm * 128 + mi * 16 + quad * 4 + r;
                    const size_t rowoff = (size_t)(m0 + rl) * N;
                    #pragma unroll
                    for (int ni = 0; ni < 4; ++ni) {
                        const int cl = wn * 64 + ni * 16 + l16;
                        float g = bf2f(Ex[rl * 132 + cl]);
                        float u = acc[mi][ni][r];
                        float sig = 1.0f / (1.0f + exp2f(-g * 1.4426950408889634f));
                        C[rowoff + (n0 >> 1) + cl] = f2bf(g * sig * u);
                    }
                }
        }
        return;
    }

    #pragma unroll
    for (int mi = 0; mi < 8; ++mi) {
        #pragma unroll
        for (int r = 0; r < 4; ++r) {
            const int m = m0 + wm * 128 + mi * 16 + quad * 4 + r;
            const size_t rowoff = (size_t)m * N;
            #pragma unroll
            for (int ni = 0; ni < 4; ++ni) {
                const int n = n0 + wn * 64 + ni * 16 + l16;
                float v = acc[mi][ni][r];
                if constexpr (ATOMIC) {
                    if (R != nullptr && blockIdx.z == 0) v += R[rowoff + n];
                    atomicAdd((float*)&C[rowoff + n], v);
                } else if constexpr (std::is_same<OutT, float>::value) {
                    if (R != nullptr) v += R[rowoff + n];
                    C[rowoff + n] = v;
                } else {
                    C[rowoff + n] = f2bf(v);
                }
            }
        }
    }
}

// ---------------- RoPE prep: qkv bf16 [S,4096] -> q_r [NH,S,HD], k_r [NKV,S,HD] ----
__global__ __launch_bounds__(256) void rope_prep(
    const unsigned short* __restrict__ qkv, const float* __restrict__ cosp,
    const float* __restrict__ sinp,
    unsigned short* __restrict__ q_r, unsigned short* __restrict__ k_r)
{
    const int s = blockIdx.x;
    const int tid = threadIdx.x;
    const unsigned short* row = qkv + (size_t)s * 4096;
    #pragma unroll
    for (int j = 0; j < 12; j++) {          // 3072 = q(2048) + k(1024)
        int e = j * 256 + tid;
        int head = e >> 7, hd = e & 127;
        float v = bf2f(row[e]);
        float part = (hd < 64) ? -bf2f(row[e + 64]) : bf2f(row[e - 64]);
        float c  = cosp[s * HD + hd];
        float sn = sinp[s * HD + hd];
        unsigned short ob = f2bf(v * c + part * sn);
        if (head < NH) q_r[((size_t)head * S + s) * HD + hd] = ob;
        else           k_r[((size_t)(head - NH) * S + s) * HD + hd] = ob;
    }
}

// ---------------- V transpose: qkv bf16 cols 3072..4095 -> v_t TILED bf16 ----------
// v_t layout: [NKV][S/32 key-tiles][HD=128][32 keys]  (each tile = contiguous 8 KB)
__global__ __launch_bounds__(256) void v_trans(
    const unsigned short* __restrict__ qkv, unsigned short* __restrict__ v_t)
{
    __shared__ unsigned short t[128][66];
    const int s0 = blockIdx.x * 64;
    const int kv = blockIdx.y;
    const int tid = threadIdx.x;
    const unsigned short* base = qkv + 3072 + kv * HD;
    #pragma unroll
    for (int i = 0; i < 4; i++) {
        int idx = i * 256 + tid;            // one u16v8 each, 1024 total
        int s_l = idx >> 4;
        int hd8 = (idx & 15) * 8;
        u16v8 v = *(const u16v8*)(base + (size_t)(s0 + s_l) * 4096 + hd8);
        #pragma unroll
        for (int j = 0; j < 8; j++) t[hd8 + j][s_l] = v[j];
    }
    __syncthreads();
    #pragma unroll
    for (int i = 0; i < 8; i++) {
        int idx = i * 256 + tid;            // 2048 u16v4 chunks
        int d  = idx >> 4;                  // 0..127
        int rm = idx & 15;
        int hh = rm >> 3;                   // key-tile half 0/1
        int s4 = (rm & 7) * 4;              // 0..28 within tile
        u16v4 o;
        o[0] = t[d][hh * 32 + s4];     o[1] = t[d][hh * 32 + s4 + 1];
        o[2] = t[d][hh * 32 + s4 + 2]; o[3] = t[d][hh * 32 + s4 + 3];
        size_t tile = (size_t)kv * (S / 32) + (s0 >> 5) + hh;
        *(u16v4*)&v_t[(tile * 128 + d) * 32 + s4] = o;
    }
}

// ---------------- Flash attention (LDS-staged K/V, swizzled) ----------------
__global__ __launch_bounds__(256) void attn_kernel(
    const unsigned short* __restrict__ q_r, const unsigned short* __restrict__ k_r,
    const unsigned short* __restrict__ v_t, unsigned short* __restrict__ out)
{
    __shared__ unsigned short Ks[32 * 128];
    __shared__ unsigned short Vs[144 * 32];
    __shared__ unsigned short P[4][16][40];
    const int h = blockIdx.y, kv = h >> 1;
    const int qb0 = blockIdx.x * 64;
    const int tid = threadIdx.x;
    const int wave = tid >> 6, lane = tid & 63, quad = lane >> 4, l16 = lane & 15;
    const int qb = qb0 + wave * 16;
    const unsigned short* Q  = q_r + (size_t)h * S * HD;
    const unsigned short* K  = k_r + (size_t)kv * S * HD;
    const unsigned short* Vh = v_t + (size_t)kv * (S / 32) * (128 * 32);

    // ones rows for the l-sum tile (rows 129..143 zero)
    {
        int e0 = tid * 2;
        Vs[128 * 32 + e0]     = (e0     < 32) ? (unsigned short)0x3F80 : (unsigned short)0;
        Vs[128 * 32 + e0 + 1] = (e0 + 1 < 32) ? (unsigned short)0x3F80 : (unsigned short)0;
    }

    bf16x8 aq[4];
    #pragma unroll
    for (int t = 0; t < 4; t++)
        aq[t] = *(const bf16x8*)&Q[(size_t)(qb + l16) * HD + t * 32 + quad * 8];

    f32x4 o[9] = {};                       // o[8] = row-sum accumulator (l)
    float m_i[4] = { -__builtin_inff(), -__builtin_inff(), -__builtin_inff(), -__builtin_inff() };
    const float SCL = 0.08838834764831845f * 1.4426950408889634f;  // 1/sqrt(HD)*log2(e)
    const int nk = (qb0 >> 5) + 2;

    const int kr  = (lane >> 4);           // K: row within 4-row issue group
    const int kbl = lane & 15;             // K: 16B block within 256B row
    const int vr  = (lane >> 2);           // V: row within 16-row issue group
    const int vbl = lane & 3;              // V: 16B block within 64B row

    for (int kb = 0; kb < nk; kb++) {
        const int kbase = kb * 32;
        const unsigned short* Ktile = K + (size_t)kbase * HD;
        const unsigned short* Vtile = Vh + (size_t)kb * (128 * 32);
        #pragma unroll
        for (int e = 0; e < 2; e++) {
            int r = wave * 8 + e * 4 + kr;
            async16(Ktile + r * 128 + ((kbl ^ (r & 15)) * 8), &Ks[(wave * 8 + e * 4) * 128]);
        }
        #pragma unroll
        for (int e = 0; e < 2; e++) {
            int d = wave * 32 + e * 16 + vr;
            async16(Vtile + d * 32 + ((vbl ^ (d & 3)) * 8), &Vs[(wave * 32 + e * 16) * 32]);
        }
        __syncthreads();   // vmcnt(0) drain: tiles landed

        if (kbase <= qb + 15) {
            f32x4 s0 = {0.f, 0.f, 0.f, 0.f}, s1 = {0.f, 0.f, 0.f, 0.f};
            #pragma unroll
            for (int t = 0; t < 4; t++) {
                int b = t * 4 + quad;
                bf16x8 b0 = *(const bf16x8*)&Ks[l16 * 128 + ((b ^ l16) * 8)];
                bf16x8 b1 = *(const bf16x8*)&Ks[(16 + l16) * 128 + ((b ^ l16) * 8)];
                s0 = __builtin_amdgcn_mfma_f32_16x16x32_bf16(aq[t], b0, s0, 0, 0, 0);
                s1 = __builtin_amdgcn_mfma_f32_16x16x32_bf16(aq[t], b1, s1, 0, 0, 0);
            }
            float alpha[4];
            #pragma unroll
            for (int r = 0; r < 4; r++) {
                const int q = qb + quad * 4 + r;
                float v0 = (kbase + l16      <= q) ? s0[r] * SCL : -__builtin_inff();
                float v1 = (kbase + 16 + l16 <= q) ? s1[r] * SCL : -__builtin_inff();
                float mx = fmaxf(v0, v1);
                #pragma unroll
                for (int d = 1; d < 16; d <<= 1) mx = fmaxf(mx, __shfl_xor(mx, d));
                float nm = fmaxf(m_i[r], mx);
                alpha[r] = exp2f(m_i[r] - nm);
                m_i[r] = nm;
                s0[r] = exp2f(v0 - nm);
                s1[r] = exp2f(v1 - nm);
            }
            #pragma unroll
            for (int ni = 0; ni < 9; ni++)
                #pragma unroll
                for (int r = 0; r < 4; r++) o[ni][r] *= alpha[r];
            #pragma unroll
            for (int r = 0; r < 4; r++) {
                P[wave][quad * 4 + r][l16]      = f2bf(s0[r]);
                P[wave][quad * 4 + r][16 + l16] = f2bf(s1[r]);
            }
            asm volatile("s_waitcnt lgkmcnt(0)" ::: "memory");
            bf16x8 ap = *(const bf16x8*)&P[wave][l16][quad * 8];
            #pragma unroll
            for (int ni = 0; ni < 9; ni++) {
                int d = ni * 16 + l16;
                bf16x8 bv = *(const bf16x8*)&Vs[d * 32 + ((quad ^ (d & 3)) * 8)];
                o[ni] = __builtin_amdgcn_mfma_f32_16x16x32_bf16(ap, bv, o[ni], 0, 0, 0);
            }
        }
        __syncthreads();   // all waves done reading before next tile staged
    }
    #pragma unroll
    for (int r = 0; r < 4; r++) {
        float lsum = __shfl(o[8][r], quad * 16);   // l lives in lane (l16=0, quad)
        const float inv = 1.0f / lsum;
        const int qrow = qb + quad * 4 + r;
        #pragma unroll
        for (int ni = 0; ni < 8; ni++)
            out[(size_t)qrow * (NH * HD) + h * HD + ni * 16 + l16] = f2bf(o[ni][r] * inv);
    }
}

// ---------------- launch ----------------
extern "C" void kernel_launch(void* const* d_in, const int* in_sizes, int n_in,
                              void* d_out, int out_size, void* d_ws, size_t ws_size,
                              hipStream_t stream) {
    const float* hs   = (const float*)d_in[0];   // [1,S,H] fp32
    const float* W    = (const float*)d_in[1];   // flat weights fp32
    const float* ln1  = (const float*)d_in[2];
    const float* ln2  = (const float*)d_in[3];
    const float* cosp = (const float*)d_in[4];   // [S,HD]
    const float* sinp = (const float*)d_in[5];
    float* out = (float*)d_out;                  // [S,H] fp32
    char* ws = (char*)d_ws;

    unsigned short* Wbuf   = (unsigned short*)(ws + 0);                  // 64 MiB staged bf16 weights
    unsigned short* x_norm = (unsigned short*)(ws + (64ull  << 20));     // 8 MiB
    unsigned short* qkv    = (unsigned short*)(ws + (72ull  << 20));     // 16 MiB bf16
    unsigned short* act    = (unsigned short*)(ws + (72ull  << 20));     // 32 MiB bf16 (reuses qkv, dead)
    unsigned short* q_r    = (unsigned short*)(ws + (104ull << 20));     // 8 MiB
    unsigned short* k_r    = (unsigned short*)(ws + (112ull << 20));     // 4 MiB
    unsigned short* v_t    = (unsigned short*)(ws + (116ull << 20));     // 4 MiB (tiled)
    unsigned short* attn_o = (unsigned short*)(ws + (120ull << 20));     // 8 MiB

    // 1. stage qkv weights -> bf16 ; input RMSNorm
    w2bf<<<8388608 / 2048, 256, 0, stream>>>(W, Wbuf);
    rmsnorm_kernel<<<S, 256, 0, stream>>>(hs, ln1, x_norm);
    // 2. fused QKV GEMM -> qkv bf16 [S,4096]
    gemm_bf16<unsigned short, false, false, true><<<dim3(S / 128, 4096 / 128, 1), 256, 0, stream>>>(
        x_norm, Wbuf, qkv, nullptr, S, 4096, H, H, H);
    // 3. RoPE + layouts
    rope_prep<<<S, 256, 0, stream>>>(qkv, cosp, sinp, q_r, k_r);
    v_trans<<<dim3(S / 64, NKV), 256, 0, stream>>>(qkv, v_t);
    // 4. causal flash attention
    attn_kernel<<<dim3(S / 64, NH), 256, 0, stream>>>(q_r, k_r, v_t, attn_o);
    // 5. O-proj: out = hs + attn_o @ o_w^T  (single-K, plain store + fused residual;
    //    removes memset + 8.4M atomicAdds vs split-K=2)
    w2bf<<<4194304 / 2048, 256, 0, stream>>>(W + 8388608, Wbuf);
    gemm_bf16<float, false, false, false><<<dim3(H / 128, S / 128, 1), 256, 0, stream>>>(
        attn_o, Wbuf, out, hs, S, H, H, H, H);
    // 6. post RMSNorm
    rmsnorm_kernel<<<S, 256, 0, stream>>>(out, ln2, x_norm);
    // 7. fused up|gate GEMM + SiLU epilogue -> act bf16 [S, II]  (256^2, 2-phase)
    w2bf_mlp256<<<2 * II, 256, 0, stream>>>(W + 12582912, Wbuf);
    gemm256<unsigned short, false, true><<<dim3(S / 256, (2 * II) / 256, 1), 512, 0, stream>>>(
        x_norm, Wbuf, act, nullptr, S, II, H, H, H);
    // 8. down-proj: out += act @ down_w^T  (split-K=4 atomic; residual already in out)
    w2bf<<<16777216 / 2048, 256, 0, stream>>>(W + 46137344, Wbuf);
    gemm256<float, true, false><<<dim3(S / 256, H / 256, 4), 512, 0, stream>>>(
        act, Wbuf, out, nullptr, S, H, II, II, II / 4);
}

// Round 6
// 792.375 us; speedup vs baseline: 1.1672x; 1.0913x over previous
//
#include <hip/hip_runtime.h>
#include <type_traits>
#include <cstdint>
#include <cstddef>

// ---- types ----
typedef __bf16 bf16x8 __attribute__((ext_vector_type(8)));
typedef float  f32x4  __attribute__((ext_vector_type(4)));
typedef unsigned short u16v4 __attribute__((ext_vector_type(4)));
typedef unsigned short u16v8 __attribute__((ext_vector_type(8)));

#define H    2048
#define NH   16
#define NKV  8
#define HD   128
#define II   8192
#define S    2048

__device__ __forceinline__ unsigned short f2bf(float f) {
    union { float f; unsigned u; } v; v.f = f;
    unsigned r = v.u + 0x7fffu + ((v.u >> 16) & 1u);
    return (unsigned short)(r >> 16);
}
__device__ __forceinline__ float bf2f(unsigned short b) {
    union { unsigned u; float f; } v; v.u = ((unsigned)b) << 16;
    return v.f;
}

// async global->LDS, 16B per lane. LDS dest must be wave-uniform base;
// HW adds lane*16.
__device__ __forceinline__ void async16(const unsigned short* g, const unsigned short* l) {
    __builtin_amdgcn_global_load_lds(
        (const __attribute__((address_space(1))) void*)g,
        (__attribute__((address_space(3))) void*)l, 16, 0, 0);
}

// ---------------- weight fp32 -> bf16 (8 elems/thread) ----------------
__global__ __launch_bounds__(256) void w2bf(const float* __restrict__ src,
                                            unsigned short* __restrict__ dst)
{
    const size_t i = (size_t)blockIdx.x * 256 + threadIdx.x;
    float4 a = ((const float4*)src)[2 * i];
    float4 b = ((const float4*)src)[2 * i + 1];
    u16v8 o;
    o[0] = f2bf(a.x); o[1] = f2bf(a.y); o[2] = f2bf(a.z); o[3] = f2bf(a.w);
    o[4] = f2bf(b.x); o[5] = f2bf(b.y); o[6] = f2bf(b.z); o[7] = f2bf(b.w);
    ((u16v8*)dst)[i] = o;
}

// ---- mlp weights fp32 -> bf16 with up/gate interleave for 256-row B-tiles ----
__global__ __launch_bounds__(256) void w2bf_mlp256(const float* __restrict__ src,
                                                   unsigned short* __restrict__ dst)
{
    const int p = blockIdx.x;
    const int g = p >> 8, r = p & 255;
    const int half = r >> 7;
    const int c = (g << 7) + (r & 127);
    const float* s = src + ((size_t)half * II + c) * H;
    unsigned short* d = dst + (size_t)p * H;
    const int t = threadIdx.x;
    float4 a = ((const float4*)s)[2 * t];
    float4 b = ((const float4*)s)[2 * t + 1];
    u16v8 o;
    o[0] = f2bf(a.x); o[1] = f2bf(a.y); o[2] = f2bf(a.z); o[3] = f2bf(a.w);
    o[4] = f2bf(b.x); o[5] = f2bf(b.y); o[6] = f2bf(b.z); o[7] = f2bf(b.w);
    *(u16v8*)&d[t * 8] = o;
}

// ---------------- RMSNorm: fp32 in -> bf16 out ----------------
__global__ __launch_bounds__(256) void rmsnorm_kernel(
    const float* __restrict__ x, const float* __restrict__ w,
    unsigned short* __restrict__ out)
{
    __shared__ float red[4];
    const int row = blockIdx.x;
    const int tid = threadIdx.x;
    const float* xr = x + (size_t)row * H;
    float4 v0 = ((const float4*)xr)[tid];
    float4 v1 = ((const float4*)xr)[256 + tid];
    float s = v0.x*v0.x + v0.y*v0.y + v0.z*v0.z + v0.w*v0.w
            + v1.x*v1.x + v1.y*v1.y + v1.z*v1.z + v1.w*v1.w;
    #pragma unroll
    for (int o = 1; o < 64; o <<= 1) s += __shfl_xor(s, o);
    if ((tid & 63) == 0) red[tid >> 6] = s;
    __syncthreads();
    float tot = red[0] + red[1] + red[2] + red[3];
    float rinv = rsqrtf(tot * (1.0f / (float)H) + 1e-6f);
    float4 w0 = ((const float4*)w)[tid];
    float4 w1 = ((const float4*)w)[256 + tid];
    u16v4 o0, o1;
    o0[0] = f2bf(v0.x * w0.x * rinv); o0[1] = f2bf(v0.y * w0.y * rinv);
    o0[2] = f2bf(v0.z * w0.z * rinv); o0[3] = f2bf(v0.w * w0.w * rinv);
    o1[0] = f2bf(v1.x * w1.x * rinv); o1[1] = f2bf(v1.y * w1.y * rinv);
    o1[2] = f2bf(v1.z * w1.z * rinv); o1[3] = f2bf(v1.w * w1.w * rinv);
    unsigned short* orow = out + (size_t)row * H;
    *(u16v4*)&orow[tid * 4]        = o0;
    *(u16v4*)&orow[1024 + tid * 4] = o1;
}

// ---------------- 128x128 2-phase GEMM, 2 blocks/CU (R6 TLP experiment) -------
// 256 thr = 4 waves (2M x 2N), per-wave out 64x64 = acc[4][4] (64 VGPR).
// BK=64; LDS 64 KiB (2 slots x [A 16K | B 16K]) -> 2 blocks/CU co-resident.
// Mechanism under test: gemm256's 1 block/CU means every vmcnt/barrier stall
// idles the whole CU (R1-R5: four schedules all ~37% MfmaUtil). With 2
// independent barrier domains per CU, one block's MFMA fills the other's
// stalls (m114 block-level overlap). Keeps all proven micro-structure:
// XOR swizzle (conflicts=0), raw barriers, counted vmcnt, setprio, T1 swizzle.
//
// Staging: 16 A-groups + 16 B-groups (8 rows x 64 cols each) per K-tile;
// per wave 8 loads: batch0 = {A w,4+w,8+w,12+w} + {B w, 8+w}  (6 loads,
// covers ALL A rows + B rows 0-31,64-95 = exactly p0's read set);
// batch1 = {B 4+w, 12+w} (2 loads, B rows 32-63,96-127 = p1's read set).
// Queue: p0-end vmcnt(6) forces batch1(t) before p1 reads it;
//        p1-end vmcnt(2) forces batch0(t+1) before t+1.p0. Tail: vmcnt(0)/none.
template<typename OutT, bool ATOMIC>
__global__ __launch_bounds__(256, 2) void gemm128(
    const unsigned short* __restrict__ A, const unsigned short* __restrict__ B,
    OutT* __restrict__ C, const float* __restrict__ R,
    int M, int N, int K, int lda, int kslice)
{
    __shared__ unsigned short SM[32768];   // 2 slots x [A 8192 | B 8192] shorts
    const int tid  = threadIdx.x;
    const int wave = tid >> 6, lane = tid & 63;
    const int quad = lane >> 4, l16 = lane & 15;
    const int wm = wave >> 1, wn = wave & 1;

    // T1: bijective XCD swizzle; M-tile fast (gridDim.x = M-tiles).
    const int nMt = gridDim.x;
    const int nwg = nMt * gridDim.y;
    const int orig = blockIdx.y * nMt + blockIdx.x;
    const int q8 = nwg >> 3, r8 = nwg & 7;
    const int xcd = orig & 7, lid = orig >> 3;
    const int wgid = (xcd < r8 ? xcd * (q8 + 1) : r8 * (q8 + 1) + (xcd - r8) * q8) + lid;
    const int mt = wgid % nMt, ntile = wgid / nMt;
    const int m0 = mt * 128, n0 = ntile * 128;
    const int kbeg = blockIdx.z * kslice;

    // staging geometry identical to gemm256: stored block = logical ^ (row&7),
    // row&7 == lane>>3 => source block = (lane&7)^(lane>>3).
    const int rIn  = lane >> 3;
    const int cBlk = ((lane & 7) ^ rIn) * 8;
    const unsigned short* Ab = A + (size_t)(m0 + rIn) * lda + kbeg + cBlk;
    const unsigned short* Bb = B + (size_t)(n0 + rIn) * K   + kbeg + cBlk;
    const int ga0 = wave, ga1 = 4 + wave, ga2 = 8 + wave, ga3 = 12 + wave;
    const int gb0 = wave, gb1 = 8 + wave;          // batch0: B rows 0-31, 64-95
    const int gb2 = 4 + wave, gb3 = 12 + wave;     // batch1: B rows 32-63, 96-127

    auto stgA = [&](int g, int kt, int s) {
        async16(Ab + (size_t)g * 8 * lda + kt * 64, &SM[s * 16384 + g * 512]);
    };
    auto stgB = [&](int g, int kt, int s) {
        async16(Bb + (size_t)g * 8 * K + kt * 64, &SM[s * 16384 + 8192 + g * 512]);
    };

    // fragment read addressing (stored block = logical ^ (row&7))
    const int rx   = l16 & 7;
    const int blk0 = (quad ^ rx) * 8;           // ks=0
    const int blk1 = ((4 | quad) ^ rx) * 8;     // ks=1
    const int rowA = (wm * 64 + l16) * 64;
    const int rowB = (wn * 64 + l16) * 64;

    f32x4 acc[4][4] = {};
    const int nkt = kslice >> 6;

    // prologue: tile 0 -> slot 0; batch0 (6) then batch1 (2); force batch0.
    stgA(ga0, 0, 0); stgA(ga1, 0, 0); stgA(ga2, 0, 0); stgA(ga3, 0, 0);
    stgB(gb0, 0, 0); stgB(gb1, 0, 0);
    stgB(gb2, 0, 0); stgB(gb3, 0, 0);
    asm volatile("s_waitcnt vmcnt(2)" ::: "memory");
    __builtin_amdgcn_s_barrier();

    for (int t = 0; t < nkt; ++t) {
        const int cur = t & 1, nxt = cur ^ 1;
        const bool more = (t + 1 < nkt);
        const unsigned short* Ac = &SM[cur * 16384];
        const unsigned short* Bc = Ac + 8192;
        bf16x8 af[4][2], bg[2][2];

        // ===== phase 0: read A(mi0-3)+B(ni0-1); stage batch0(t+1); 16 MFMA
        #pragma unroll
        for (int mi = 0; mi < 4; ++mi) {
            af[mi][0] = *(const bf16x8*)&Ac[rowA + mi * 1024 + blk0];
            af[mi][1] = *(const bf16x8*)&Ac[rowA + mi * 1024 + blk1];
        }
        #pragma unroll
        for (int ni = 0; ni < 2; ++ni) {
            bg[ni][0] = *(const bf16x8*)&Bc[rowB + ni * 1024 + blk0];
            bg[ni][1] = *(const bf16x8*)&Bc[rowB + ni * 1024 + blk1];
        }
        if (more) {
            stgA(ga0, t + 1, nxt); stgA(ga1, t + 1, nxt);
            stgA(ga2, t + 1, nxt); stgA(ga3, t + 1, nxt);
            stgB(gb0, t + 1, nxt); stgB(gb1, t + 1, nxt);
        }
        __builtin_amdgcn_s_barrier();
        asm volatile("s_waitcnt lgkmcnt(0)" ::: "memory");
        __builtin_amdgcn_sched_barrier(0);
        __builtin_amdgcn_s_setprio(1);
        #pragma unroll
        for (int mi = 0; mi < 4; ++mi)
            #pragma unroll
            for (int ni = 0; ni < 2; ++ni) {
                acc[mi][ni] = __builtin_amdgcn_mfma_f32_16x16x32_bf16(af[mi][0], bg[ni][0], acc[mi][ni], 0, 0, 0);
                acc[mi][ni] = __builtin_amdgcn_mfma_f32_16x16x32_bf16(af[mi][1], bg[ni][1], acc[mi][ni], 0, 0, 0);
            }
        __builtin_amdgcn_s_setprio(0);
        if (more) { asm volatile("s_waitcnt vmcnt(6)" ::: "memory"); }
        else      { asm volatile("s_waitcnt vmcnt(0)" ::: "memory"); }
        __builtin_amdgcn_s_barrier();

        // ===== phase 1: read B(ni2-3); stage batch1(t+1); 16 MFMA
        #pragma unroll
        for (int ni = 0; ni < 2; ++ni) {
            bg[ni][0] = *(const bf16x8*)&Bc[rowB + (2 + ni) * 1024 + blk0];
            bg[ni][1] = *(const bf16x8*)&Bc[rowB + (2 + ni) * 1024 + blk1];
        }
        if (more) {
            stgB(gb2, t + 1, nxt); stgB(gb3, t + 1, nxt);
        }
        __builtin_amdgcn_s_barrier();
        asm volatile("s_waitcnt lgkmcnt(0)" ::: "memory");
        __builtin_amdgcn_sched_barrier(0);
        __builtin_amdgcn_s_setprio(1);
        #pragma unroll
        for (int mi = 0; mi < 4; ++mi)
            #pragma unroll
            for (int ni = 0; ni < 2; ++ni) {
                acc[mi][2 + ni] = __builtin_amdgcn_mfma_f32_16x16x32_bf16(af[mi][0], bg[ni][0], acc[mi][2 + ni], 0, 0, 0);
                acc[mi][2 + ni] = __builtin_amdgcn_mfma_f32_16x16x32_bf16(af[mi][1], bg[ni][1], acc[mi][2 + ni], 0, 0, 0);
            }
        __builtin_amdgcn_s_setprio(0);
        if (more) { asm volatile("s_waitcnt vmcnt(2)" ::: "memory"); }
        __builtin_amdgcn_s_barrier();
    }

    #pragma unroll
    for (int mi = 0; mi < 4; ++mi) {
        #pragma unroll
        for (int r = 0; r < 4; ++r) {
            const int m = m0 + wm * 64 + mi * 16 + quad * 4 + r;
            const size_t rowoff = (size_t)m * N;
            #pragma unroll
            for (int ni = 0; ni < 4; ++ni) {
                const int n = n0 + wn * 64 + ni * 16 + l16;
                float v = acc[mi][ni][r];
                if constexpr (ATOMIC) {
                    if (R != nullptr && blockIdx.z == 0) v += R[rowoff + n];
                    atomicAdd((float*)&C[rowoff + n], v);
                } else if constexpr (std::is_same<OutT, float>::value) {
                    if (R != nullptr) v += R[rowoff + n];
                    C[rowoff + n] = v;
                } else {
                    C[rowoff + n] = f2bf(v);
                }
            }
        }
    }
}

// ---------------- 256x256 2-PHASE GEMM (control; up|gate SILU only) -----------
// R5-measured: 155 us / 37% MfmaUtil / conflicts 0. Kept byte-identical as the
// within-session control against gemm128 (down-proj per-TF comparison).
template<typename OutT, bool ATOMIC, bool SILU>
__global__ __launch_bounds__(512, 2) void gemm256(
    const unsigned short* __restrict__ A, const unsigned short* __restrict__ B,
    OutT* __restrict__ C, const float* __restrict__ R,
    int M, int N, int K, int lda, int kslice)
{
    __shared__ unsigned short SM[65536];   // [slot*32768]:  A 16384 | B 16384
    const int tid  = threadIdx.x;
    const int wave = tid >> 6, lane = tid & 63;
    const int quad = lane >> 4, l16 = lane & 15;
    const int wm = wave >> 2, wn = wave & 3;

    const int nMt = gridDim.x;
    const int nwg = nMt * gridDim.y;
    const int orig = blockIdx.y * nMt + blockIdx.x;
    const int q8 = nwg >> 3, r8 = nwg & 7;
    const int xcd = orig & 7, lid = orig >> 3;
    const int wgid = (xcd < r8 ? xcd * (q8 + 1) : r8 * (q8 + 1) + (xcd - r8) * q8) + lid;
    const int mt = wgid % nMt, ntile = wgid / nMt;
    const int m0 = mt * 256, n0 = ntile * 256;
    const int kbeg = blockIdx.z * kslice;

    const int rIn  = lane >> 3;
    const int cBlk = ((lane & 7) ^ rIn) * 8;
    const unsigned short* Ab = A + (size_t)(m0 + rIn) * lda + kbeg + cBlk;
    const unsigned short* Bb = B + (size_t)(n0 + rIn) * K   + kbeg + cBlk;
    const int ga0 = wave,      ga1 = 16 + wave, ga2 = 8 + wave, ga3 = 24 + wave;
    const int gbB = (wave & 3) + ((wave >> 2) << 4);
    const int gb0 = gbB, gb1 = gbB + 8;            // Bset0
    const int gb2 = gbB + 4, gb3 = gbB + 12;       // Bset1

    auto stgA = [&](int g, int kt, int s) {
        async16(Ab + (size_t)g * 8 * lda + kt * 64, &SM[s * 32768 + g * 512]);
    };
    auto stgB = [&](int g, int kt, int s) {
        async16(Bb + (size_t)g * 8 * K + kt * 64, &SM[s * 32768 + 16384 + g * 512]);
    };

    const int rx   = l16 & 7;
    const int blk0 = (quad ^ rx) * 8;           // ks=0
    const int blk1 = ((4 | quad) ^ rx) * 8;     // ks=1
    const int rowA = (wm * 128 + l16) * 64;
    const int rowB = (wn * 64 + l16) * 64;

    f32x4 acc[8][4] = {};
    const int nkt = kslice >> 6;

    stgA(ga0, 0, 0); stgA(ga1, 0, 0); stgA(ga2, 0, 0); stgA(ga3, 0, 0);
    stgB(gb0, 0, 0); stgB(gb1, 0, 0);
    stgB(gb2, 0, 0); stgB(gb3, 0, 0);
    asm volatile("s_waitcnt vmcnt(2)" ::: "memory");
    __builtin_amdgcn_s_barrier();

    for (int t = 0; t < nkt; ++t) {
        const int cur = t & 1, nxt = cur ^ 1;
        const bool more = (t + 1 < nkt);
        const unsigned short* Ac = &SM[cur * 32768];
        const unsigned short* Bc = Ac + 16384;
        bf16x8 af[8][2], bg[2][2];

        // ===== phase 0
        #pragma unroll
        for (int mi = 0; mi < 8; ++mi) {
            af[mi][0] = *(const bf16x8*)&Ac[rowA + mi * 1024 + blk0];
            af[mi][1] = *(const bf16x8*)&Ac[rowA + mi * 1024 + blk1];
        }
        #pragma unroll
        for (int ni = 0; ni < 2; ++ni) {
            bg[ni][0] = *(const bf16x8*)&Bc[rowB + ni * 1024 + blk0];
            bg[ni][1] = *(const bf16x8*)&Bc[rowB + ni * 1024 + blk1];
        }
        if (more) {
            stgA(ga0, t + 1, nxt); stgA(ga1, t + 1, nxt);
            stgA(ga2, t + 1, nxt); stgA(ga3, t + 1, nxt);
            stgB(gb0, t + 1, nxt); stgB(gb1, t + 1, nxt);
        }
        __builtin_amdgcn_s_barrier();
        asm volatile("s_waitcnt lgkmcnt(0)" ::: "memory");
        __builtin_amdgcn_sched_barrier(0);
        __builtin_amdgcn_s_setprio(1);
        #pragma unroll
        for (int mi = 0; mi < 8; ++mi)
            #pragma unroll
            for (int ni = 0; ni < 2; ++ni) {
                acc[mi][ni] = __builtin_amdgcn_mfma_f32_16x16x32_bf16(af[mi][0], bg[ni][0], acc[mi][ni], 0, 0, 0);
                acc[mi][ni] = __builtin_amdgcn_mfma_f32_16x16x32_bf16(af[mi][1], bg[ni][1], acc[mi][ni], 0, 0, 0);
            }
        __builtin_amdgcn_s_setprio(0);
        if (more) { asm volatile("s_waitcnt vmcnt(6)" ::: "memory"); }
        else      { asm volatile("s_waitcnt vmcnt(0)" ::: "memory"); }
        __builtin_amdgcn_s_barrier();

        // ===== phase 1
        #pragma unroll
        for (int ni = 0; ni < 2; ++ni) {
            bg[ni][0] = *(const bf16x8*)&Bc[rowB + (2 + ni) * 1024 + blk0];
            bg[ni][1] = *(const bf16x8*)&Bc[rowB + (2 + ni) * 1024 + blk1];
        }
        if (more) {
            stgB(gb2, t + 1, nxt); stgB(gb3, t + 1, nxt);
        }
        __builtin_amdgcn_s_barrier();
        asm volatile("s_waitcnt lgkmcnt(0)" ::: "memory");
        __builtin_amdgcn_sched_barrier(0);
        __builtin_amdgcn_s_setprio(1);
        #pragma unroll
        for (int mi = 0; mi < 8; ++mi)
            #pragma unroll
            for (int ni = 0; ni < 2; ++ni) {
                acc[mi][2 + ni] = __builtin_amdgcn_mfma_f32_16x16x32_bf16(af[mi][0], bg[ni][0], acc[mi][2 + ni], 0, 0, 0);
                acc[mi][2 + ni] = __builtin_amdgcn_mfma_f32_16x16x32_bf16(af[mi][1], bg[ni][1], acc[mi][2 + ni], 0, 0, 0);
            }
        __builtin_amdgcn_s_setprio(0);
        if (more) { asm volatile("s_waitcnt vmcnt(2)" ::: "memory"); }
        __builtin_amdgcn_s_barrier();
    }

    if constexpr (SILU) {
        unsigned short* Ex = SM;                      // 256*132*2 B = 66 KiB
        if (wn >= 2) {
            #pragma unroll
            for (int mi = 0; mi < 8; ++mi)
                #pragma unroll
                for (int r = 0; r < 4; ++r) {
                    const int rl = wm * 128 + mi * 16 + quad * 4 + r;
                    #pragma unroll
                    for (int ni = 0; ni < 4; ++ni)
                        Ex[rl * 132 + (wn - 2) * 64 + ni * 16 + l16] = f2bf(acc[mi][ni][r]);
                }
        }
        __builtin_amdgcn_s_barrier();
        if (wn < 2) {
            #pragma unroll
            for (int mi = 0; mi < 8; ++mi)
                #pragma unroll
                for (int r = 0; r < 4; ++r) {
                    const int rl = wm * 128 + mi * 16 + quad * 4 + r;
                    const size_t rowoff = (size_t)(m0 + rl) * N;
                    #pragma unroll
                    for (int ni = 0; ni < 4; ++ni) {
                        const int cl = wn * 64 + ni * 16 + l16;
                        float g = bf2f(Ex[rl * 132 + cl]);
                        float u = acc[mi][ni][r];
                        float sig = 1.0f / (1.0f + exp2f(-g * 1.4426950408889634f));
                        C[rowoff + (n0 >> 1) + cl] = f2bf(g * sig * u);
                    }
                }
        }
        return;
    }

    #pragma unroll
    for (int mi = 0; mi < 8; ++mi) {
        #pragma unroll
        for (int r = 0; r < 4; ++r) {
            const int m = m0 + wm * 128 + mi * 16 + quad * 4 + r;
            const size_t rowoff = (size_t)m * N;
            #pragma unroll
            for (int ni = 0; ni < 4; ++ni) {
                const int n = n0 + wn * 64 + ni * 16 + l16;
                float v = acc[mi][ni][r];
                if constexpr (ATOMIC) {
                    if (R != nullptr && blockIdx.z == 0) v += R[rowoff + n];
                    atomicAdd((float*)&C[rowoff + n], v);
                } else if constexpr (std::is_same<OutT, float>::value) {
                    if (R != nullptr) v += R[rowoff + n];
                    C[rowoff + n] = v;
                } else {
                    C[rowoff + n] = f2bf(v);
                }
            }
        }
    }
}

// ---------------- RoPE prep: qkv bf16 [S,4096] -> q_r [NH,S,HD], k_r [NKV,S,HD] ----
__global__ __launch_bounds__(256) void rope_prep(
    const unsigned short* __restrict__ qkv, const float* __restrict__ cosp,
    const float* __restrict__ sinp,
    unsigned short* __restrict__ q_r, unsigned short* __restrict__ k_r)
{
    const int s = blockIdx.x;
    const int tid = threadIdx.x;
    const unsigned short* row = qkv + (size_t)s * 4096;
    #pragma unroll
    for (int j = 0; j < 12; j++) {          // 3072 = q(2048) + k(1024)
        int e = j * 256 + tid;
        int head = e >> 7, hd = e & 127;
        float v = bf2f(row[e]);
        float part = (hd < 64) ? -bf2f(row[e + 64]) : bf2f(row[e - 64]);
        float c  = cosp[s * HD + hd];
        float sn = sinp[s * HD + hd];
        unsigned short ob = f2bf(v * c + part * sn);
        if (head < NH) q_r[((size_t)head * S + s) * HD + hd] = ob;
        else           k_r[((size_t)(head - NH) * S + s) * HD + hd] = ob;
    }
}

// ---------------- V transpose: qkv bf16 cols 3072..4095 -> v_t TILED bf16 ----------
__global__ __launch_bounds__(256) void v_trans(
    const unsigned short* __restrict__ qkv, unsigned short* __restrict__ v_t)
{
    __shared__ unsigned short t[128][66];
    const int s0 = blockIdx.x * 64;
    const int kv = blockIdx.y;
    const int tid = threadIdx.x;
    const unsigned short* base = qkv + 3072 + kv * HD;
    #pragma unroll
    for (int i = 0; i < 4; i++) {
        int idx = i * 256 + tid;            // one u16v8 each, 1024 total
        int s_l = idx >> 4;
        int hd8 = (idx & 15) * 8;
        u16v8 v = *(const u16v8*)(base + (size_t)(s0 + s_l) * 4096 + hd8);
        #pragma unroll
        for (int j = 0; j < 8; j++) t[hd8 + j][s_l] = v[j];
    }
    __syncthreads();
    #pragma unroll
    for (int i = 0; i < 8; i++) {
        int idx = i * 256 + tid;            // 2048 u16v4 chunks
        int d  = idx >> 4;                  // 0..127
        int rm = idx & 15;
        int hh = rm >> 3;                   // key-tile half 0/1
        int s4 = (rm & 7) * 4;              // 0..28 within tile
        u16v4 o;
        o[0] = t[d][hh * 32 + s4];     o[1] = t[d][hh * 32 + s4 + 1];
        o[2] = t[d][hh * 32 + s4 + 2]; o[3] = t[d][hh * 32 + s4 + 3];
        size_t tile = (size_t)kv * (S / 32) + (s0 >> 5) + hh;
        *(u16v4*)&v_t[(tile * 128 + d) * 32 + s4] = o;
    }
}

// ---------------- Flash attention (LDS-staged K/V, swizzled) ----------------
__global__ __launch_bounds__(256) void attn_kernel(
    const unsigned short* __restrict__ q_r, const unsigned short* __restrict__ k_r,
    const unsigned short* __restrict__ v_t, unsigned short* __restrict__ out)
{
    __shared__ unsigned short Ks[32 * 128];
    __shared__ unsigned short Vs[144 * 32];
    __shared__ unsigned short P[4][16][40];
    const int h = blockIdx.y, kv = h >> 1;
    const int qb0 = blockIdx.x * 64;
    const int tid = threadIdx.x;
    const int wave = tid >> 6, lane = tid & 63, quad = lane >> 4, l16 = lane & 15;
    const int qb = qb0 + wave * 16;
    const unsigned short* Q  = q_r + (size_t)h * S * HD;
    const unsigned short* K  = k_r + (size_t)kv * S * HD;
    const unsigned short* Vh = v_t + (size_t)kv * (S / 32) * (128 * 32);

    {
        int e0 = tid * 2;
        Vs[128 * 32 + e0]     = (e0     < 32) ? (unsigned short)0x3F80 : (unsigned short)0;
        Vs[128 * 32 + e0 + 1] = (e0 + 1 < 32) ? (unsigned short)0x3F80 : (unsigned short)0;
    }

    bf16x8 aq[4];
    #pragma unroll
    for (int t = 0; t < 4; t++)
        aq[t] = *(const bf16x8*)&Q[(size_t)(qb + l16) * HD + t * 32 + quad * 8];

    f32x4 o[9] = {};                       // o[8] = row-sum accumulator (l)
    float m_i[4] = { -__builtin_inff(), -__builtin_inff(), -__builtin_inff(), -__builtin_inff() };
    const float SCL = 0.08838834764831845f * 1.4426950408889634f;  // 1/sqrt(HD)*log2(e)
    const int nk = (qb0 >> 5) + 2;

    const int kr  = (lane >> 4);
    const int kbl = lane & 15;
    const int vr  = (lane >> 2);
    const int vbl = lane & 3;

    for (int kb = 0; kb < nk; kb++) {
        const int kbase = kb * 32;
        const unsigned short* Ktile = K + (size_t)kbase * HD;
        const unsigned short* Vtile = Vh + (size_t)kb * (128 * 32);
        #pragma unroll
        for (int e = 0; e < 2; e++) {
            int r = wave * 8 + e * 4 + kr;
            async16(Ktile + r * 128 + ((kbl ^ (r & 15)) * 8), &Ks[(wave * 8 + e * 4) * 128]);
        }
        #pragma unroll
        for (int e = 0; e < 2; e++) {
            int d = wave * 32 + e * 16 + vr;
            async16(Vtile + d * 32 + ((vbl ^ (d & 3)) * 8), &Vs[(wave * 32 + e * 16) * 32]);
        }
        __syncthreads();   // vmcnt(0) drain: tiles landed

        if (kbase <= qb + 15) {
            f32x4 s0 = {0.f, 0.f, 0.f, 0.f}, s1 = {0.f, 0.f, 0.f, 0.f};
            #pragma unroll
            for (int t = 0; t < 4; t++) {
                int b = t * 4 + quad;
                bf16x8 b0 = *(const bf16x8*)&Ks[l16 * 128 + ((b ^ l16) * 8)];
                bf16x8 b1 = *(const bf16x8*)&Ks[(16 + l16) * 128 + ((b ^ l16) * 8)];
                s0 = __builtin_amdgcn_mfma_f32_16x16x32_bf16(aq[t], b0, s0, 0, 0, 0);
                s1 = __builtin_amdgcn_mfma_f32_16x16x32_bf16(aq[t], b1, s1, 0, 0, 0);
            }
            float alpha[4];
            #pragma unroll
            for (int r = 0; r < 4; r++) {
                const int q = qb + quad * 4 + r;
                float v0 = (kbase + l16      <= q) ? s0[r] * SCL : -__builtin_inff();
                float v1 = (kbase + 16 + l16 <= q) ? s1[r] * SCL : -__builtin_inff();
                float mx = fmaxf(v0, v1);
                #pragma unroll
                for (int d = 1; d < 16; d <<= 1) mx = fmaxf(mx, __shfl_xor(mx, d));
                float nm = fmaxf(m_i[r], mx);
                alpha[r] = exp2f(m_i[r] - nm);
                m_i[r] = nm;
                s0[r] = exp2f(v0 - nm);
                s1[r] = exp2f(v1 - nm);
            }
            #pragma unroll
            for (int ni = 0; ni < 9; ni++)
                #pragma unroll
                for (int r = 0; r < 4; r++) o[ni][r] *= alpha[r];
            #pragma unroll
            for (int r = 0; r < 4; r++) {
                P[wave][quad * 4 + r][l16]      = f2bf(s0[r]);
                P[wave][quad * 4 + r][16 + l16] = f2bf(s1[r]);
            }
            asm volatile("s_waitcnt lgkmcnt(0)" ::: "memory");
            bf16x8 ap = *(const bf16x8*)&P[wave][l16][quad * 8];
            #pragma unroll
            for (int ni = 0; ni < 9; ni++) {
                int d = ni * 16 + l16;
                bf16x8 bv = *(const bf16x8*)&Vs[d * 32 + ((quad ^ (d & 3)) * 8)];
                o[ni] = __builtin_amdgcn_mfma_f32_16x16x32_bf16(ap, bv, o[ni], 0, 0, 0);
            }
        }
        __syncthreads();
    }
    #pragma unroll
    for (int r = 0; r < 4; r++) {
        float lsum = __shfl(o[8][r], quad * 16);
        const float inv = 1.0f / lsum;
        const int qrow = qb + quad * 4 + r;
        #pragma unroll
        for (int ni = 0; ni < 8; ni++)
            out[(size_t)qrow * (NH * HD) + h * HD + ni * 16 + l16] = f2bf(o[ni][r] * inv);
    }
}

// ---------------- launch ----------------
extern "C" void kernel_launch(void* const* d_in, const int* in_sizes, int n_in,
                              void* d_out, int out_size, void* d_ws, size_t ws_size,
                              hipStream_t stream) {
    const float* hs   = (const float*)d_in[0];   // [1,S,H] fp32
    const float* W    = (const float*)d_in[1];   // flat weights fp32
    const float* ln1  = (const float*)d_in[2];
    const float* ln2  = (const float*)d_in[3];
    const float* cosp = (const float*)d_in[4];   // [S,HD]
    const float* sinp = (const float*)d_in[5];
    float* out = (float*)d_out;                  // [S,H] fp32
    char* ws = (char*)d_ws;

    unsigned short* Wbuf   = (unsigned short*)(ws + 0);                  // 64 MiB staged bf16 weights
    unsigned short* x_norm = (unsigned short*)(ws + (64ull  << 20));     // 8 MiB
    unsigned short* qkv    = (unsigned short*)(ws + (72ull  << 20));     // 16 MiB bf16
    unsigned short* act    = (unsigned short*)(ws + (72ull  << 20));     // 32 MiB bf16 (reuses qkv, dead)
    unsigned short* q_r    = (unsigned short*)(ws + (104ull << 20));     // 8 MiB
    unsigned short* k_r    = (unsigned short*)(ws + (112ull << 20));     // 4 MiB
    unsigned short* v_t    = (unsigned short*)(ws + (116ull << 20));     // 4 MiB (tiled)
    unsigned short* attn_o = (unsigned short*)(ws + (120ull << 20));     // 8 MiB

    // 1. stage qkv weights -> bf16 ; input RMSNorm
    w2bf<<<8388608 / 2048, 256, 0, stream>>>(W, Wbuf);
    rmsnorm_kernel<<<S, 256, 0, stream>>>(hs, ln1, x_norm);
    // 2. fused QKV GEMM -> qkv bf16 [S,4096]  (gemm128: 512 blocks = 2/CU TLP)
    gemm128<unsigned short, false><<<dim3(S / 128, 4096 / 128, 1), 256, 0, stream>>>(
        x_norm, Wbuf, qkv, nullptr, S, 4096, H, H, H);
    // 3. RoPE + layouts
    rope_prep<<<S, 256, 0, stream>>>(qkv, cosp, sinp, q_r, k_r);
    v_trans<<<dim3(S / 64, NKV), 256, 0, stream>>>(qkv, v_t);
    // 4. causal flash attention
    attn_kernel<<<dim3(S / 64, NH), 256, 0, stream>>>(q_r, k_r, v_t, attn_o);
    // 5. O-proj: out = hs + attn_o @ o_w^T  (gemm128, split-K=2 atomic -> 512 blocks)
    w2bf<<<4194304 / 2048, 256, 0, stream>>>(W + 8388608, Wbuf);
    hipMemsetAsync(out, 0, (size_t)S * H * sizeof(float), stream);
    gemm128<float, true><<<dim3(S / 128, H / 128, 2), 256, 0, stream>>>(
        attn_o, Wbuf, out, hs, S, H, H, H, H / 2);
    // 6. post RMSNorm
    rmsnorm_kernel<<<S, 256, 0, stream>>>(out, ln2, x_norm);
    // 7. fused up|gate GEMM + SiLU epilogue -> act bf16 [S, II]  (gemm256 CONTROL)
    w2bf_mlp256<<<2 * II, 256, 0, stream>>>(W + 12582912, Wbuf);
    gemm256<unsigned short, false, true><<<dim3(S / 256, (2 * II) / 256, 1), 512, 0, stream>>>(
        x_norm, Wbuf, act, nullptr, S, II, H, H, H);
    // 8. down-proj: out += act @ down_w^T  (gemm128, split-K=2 atomic -> 512 blocks;
    //    per-TF comparison vs the gemm256 control decides R7's structure)
    w2bf<<<16777216 / 2048, 256, 0, stream>>>(W + 46137344, Wbuf);
    gemm128<float, true><<<dim3(S / 128, H / 128, 2), 256, 0, stream>>>(
        act, Wbuf, out, nullptr, S, H, II, II, II / 2);
}